// Round 1
// baseline (2937.991 us; speedup 1.0000x reference)
//
#include <hip/hip_runtime.h>
#include <hip/hip_bf16.h>

#define NN 100000
#define NE 3200000
#define NB 512
#define DIN 500
#define DH 64
#define HIDN 200
#define NCLS 80

// ---------- degree ----------
__global__ void deg_kernel(const int* __restrict__ dst, float* __restrict__ deg) {
    int e = blockIdx.x * blockDim.x + threadIdx.x;
    if (e < NE) atomicAdd(&deg[dst[e]], 1.0f);
}

__global__ void invdeg_kernel(float* __restrict__ deg) {
    int i = blockIdx.x * blockDim.x + threadIdx.x;
    if (i < NN) deg[i] = 1.0f / fmaxf(deg[i], 1.0f);
}

// ---------- dual GEMM: H[N,128] = in[N,K] @ [Wl | Wr], optional fused L1 row-scale ----------
// block: 256 threads, 64 rows x 128 cols; thread tile: 8 rows x 4 cols
template<int K, bool SCALE>
__launch_bounds__(256)
__global__ void gemm_dual(const float* __restrict__ in,
                          const float* __restrict__ Wl,
                          const float* __restrict__ Wr,
                          float* __restrict__ H) {
    __shared__ float x_lds[64][8];
    __shared__ float w_lds[8][128];
    __shared__ float s_lds[64];
    const int tid = threadIdx.x;
    const int row0 = blockIdx.x * 64;
    const int tc = tid & 31;        // col group (4 cols)
    const int tr = tid >> 5;        // row group (8 rows)
    // staging coords
    const int sx_row = tid >> 2;           // 0..63
    const int sx_kk  = (tid & 3) * 2;      // 0,2,4,6
    const int sw_kk  = tid >> 5;           // 0..7
    const int sw_col = (tid & 31) * 4;     // 0..124
    const float* const Wsel = (sw_col < 64) ? Wl : Wr;
    const int swc = sw_col & 63;

    float4 acc[8];
#pragma unroll
    for (int r = 0; r < 8; ++r) acc[r] = make_float4(0.f, 0.f, 0.f, 0.f);
    float pabs = 0.f;

    const int grow = row0 + sx_row;
    const bool row_ok = grow < NN;

    for (int k0 = 0; k0 < K; k0 += 8) {
        __syncthreads();
        { // stage x (2 elems / thread)
            float2 v = make_float2(0.f, 0.f);
            int gk = k0 + sx_kk;
            if (row_ok) {
                if (gk + 1 < K)      v = *(const float2*)(in + (size_t)grow * K + gk);
                else if (gk < K)     v.x = in[(size_t)grow * K + gk];
            }
            *(float2*)&x_lds[sx_row][sx_kk] = v;
            if (SCALE) pabs += fabsf(v.x) + fabsf(v.y);
        }
        { // stage w (4 cols / thread)
            float4 w = make_float4(0.f, 0.f, 0.f, 0.f);
            int gk = k0 + sw_kk;
            if (gk < K) w = *(const float4*)(Wsel + (size_t)gk * 64 + swc);
            *(float4*)&w_lds[sw_kk][sw_col] = w;
        }
        __syncthreads();
#pragma unroll
        for (int h = 0; h < 2; ++h) {
            float4 wv0 = *(const float4*)&w_lds[h*4+0][tc*4];
            float4 wv1 = *(const float4*)&w_lds[h*4+1][tc*4];
            float4 wv2 = *(const float4*)&w_lds[h*4+2][tc*4];
            float4 wv3 = *(const float4*)&w_lds[h*4+3][tc*4];
#pragma unroll
            for (int r = 0; r < 8; ++r) {
                float4 xv = *(const float4*)&x_lds[tr*8+r][h*4];
                acc[r].x += xv.x*wv0.x + xv.y*wv1.x + xv.z*wv2.x + xv.w*wv3.x;
                acc[r].y += xv.x*wv0.y + xv.y*wv1.y + xv.z*wv2.y + xv.w*wv3.y;
                acc[r].z += xv.x*wv0.z + xv.y*wv1.z + xv.z*wv2.z + xv.w*wv3.z;
                acc[r].w += xv.x*wv0.w + xv.y*wv1.w + xv.z*wv2.w + xv.w*wv3.w;
            }
        }
    }

    if (SCALE) { // reduce per-row L1 sums (4 staging threads per row)
        __syncthreads();
        x_lds[sx_row][tid & 3] = pabs;
        __syncthreads();
        if (tid < 64) {
            float ssum = x_lds[tid][0] + x_lds[tid][1] + x_lds[tid][2] + x_lds[tid][3];
            s_lds[tid] = 1.0f / fmaxf(ssum, 1e-12f);
        }
        __syncthreads();
    }

#pragma unroll
    for (int r = 0; r < 8; ++r) {
        int gr = row0 + tr * 8 + r;
        if (gr < NN) {
            float4 o = acc[r];
            if (SCALE) {
                float sc = s_lds[tr * 8 + r];
                o.x *= sc; o.y *= sc; o.z *= sc; o.w *= sc;
            }
            *(float4*)(H + (size_t)gr * 128 + tc * 4) = o;
        }
    }
}

// ---------- edge scatter: agg[dst] += H[src, 0:64]  (wave per edge) ----------
__global__ void scatter_kernel(const int* __restrict__ src, const int* __restrict__ dst,
                               const float* __restrict__ H, float* __restrict__ agg) {
    int gid = blockIdx.x * blockDim.x + threadIdx.x;
    int e = gid >> 6;
    int lane = threadIdx.x & 63;
    if (e >= NE) return;
    int si = src[e], di = dst[e];
    atomicAdd(&agg[(size_t)di * 64 + lane], H[(size_t)si * 128 + lane]);
}

// ---------- combine: e = agg*invdeg + bl + H[:,64:128] ----------
__global__ void combine_kernel(const float* __restrict__ agg, const float* __restrict__ invdeg,
                               const float* __restrict__ bl, const float* __restrict__ H,
                               float* __restrict__ eout) {
    int id = blockIdx.x * blockDim.x + threadIdx.x;
    if (id >= NN * 64) return;
    int i = id >> 6, d = id & 63;
    eout[id] = agg[id] * invdeg[i] + bl[d] + H[(size_t)i * 128 + 64 + d];
}

// ---------- global mean pool ----------
__global__ void pool_kernel(const float* __restrict__ e, const int* __restrict__ batch,
                            float* __restrict__ pl, float* __restrict__ cnt) {
    int gid = blockIdx.x * blockDim.x + threadIdx.x;
    int i = gid >> 6;
    int lane = threadIdx.x & 63;
    if (i >= NN) return;
    int b = batch[i];
    atomicAdd(&pl[b * 64 + lane], e[(size_t)i * 64 + lane]);
    if (lane == 0) atomicAdd(&cnt[b], 1.0f);
}

__global__ void poolfin_kernel(const float* __restrict__ pl, const float* __restrict__ cnt,
                               float* __restrict__ c0) {
    int id = blockIdx.x * blockDim.x + threadIdx.x;
    if (id >= NB * 64) return;
    int b = id >> 6;
    c0[id] = pl[id] / fmaxf(cnt[b], 1.0f);
}

// ---------- MLP head ----------
__global__ void lin_kernel(const float* __restrict__ in, const float* __restrict__ W,
                           const float* __restrict__ bias, float* __restrict__ out,
                           int Kd, int Dout) {
    int id = blockIdx.x * blockDim.x + threadIdx.x;
    if (id >= NB * Dout) return;
    int row = id / Dout, col = id - row * Dout;
    const float* ir = in + (size_t)row * Kd;
    float acc = bias[col];
    for (int k = 0; k < Kd; ++k) acc += ir[k] * W[(size_t)k * Dout + col];
    out[id] = acc;
}

__global__ void bnstats_kernel(const float* __restrict__ c, const float* __restrict__ g,
                               const float* __restrict__ beta, float* __restrict__ sa,
                               float* __restrict__ sb, int Dout) {
    int col = blockIdx.x;
    int tid = threadIdx.x;
    float s = 0.f, sq = 0.f;
    for (int r = tid; r < NB; r += 256) {
        float v = c[(size_t)r * Dout + col];
        s += v; sq += v * v;
    }
    __shared__ float ls[256], lq[256];
    ls[tid] = s; lq[tid] = sq;
    __syncthreads();
    for (int o = 128; o > 0; o >>= 1) {
        if (tid < o) { ls[tid] += ls[tid + o]; lq[tid] += lq[tid + o]; }
        __syncthreads();
    }
    if (tid == 0) {
        float mu = ls[0] / NB;
        float var = lq[0] / NB - mu * mu;
        float a = g[col] * rsqrtf(var + 1e-5f);
        sa[col] = a;
        sb[col] = beta[col] - mu * a;
    }
}

__global__ void bnapply_kernel(const float* __restrict__ c, const float* __restrict__ sa,
                               const float* __restrict__ sb, float* __restrict__ bv, int Dout) {
    int id = blockIdx.x * blockDim.x + threadIdx.x;
    if (id >= NB * Dout) return;
    int col = id % Dout;
    bv[id] = tanhf(c[id] * sa[col] + sb[col]);
}

extern "C" void kernel_launch(void* const* d_in, const int* in_sizes, int n_in,
                              void* d_out, int out_size, void* d_ws, size_t ws_size,
                              hipStream_t stream) {
    const float* x    = (const float*)d_in[0];
    const int* ei     = (const int*)d_in[1];
    const int* src    = ei;
    const int* dst    = ei + NE;
    const int* batch  = (const int*)d_in[2];
    const float* c1Wl = (const float*)d_in[4];
    const float* c1bl = (const float*)d_in[5];
    const float* c1Wr = (const float*)d_in[6];
    const float* c2Wl = (const float*)d_in[7];
    const float* c2bl = (const float*)d_in[8];
    const float* c2Wr = (const float*)d_in[9];
    const float* c3Wl = (const float*)d_in[10];
    const float* c3bl = (const float*)d_in[11];
    const float* c3Wr = (const float*)d_in[12];
    const float* l1W  = (const float*)d_in[13]; const float* l1b = (const float*)d_in[14];
    const float* bn1g = (const float*)d_in[15]; const float* bn1b = (const float*)d_in[16];
    const float* l2W  = (const float*)d_in[17]; const float* l2b = (const float*)d_in[18];
    const float* bn2g = (const float*)d_in[19]; const float* bn2b = (const float*)d_in[20];
    const float* l3W  = (const float*)d_in[21]; const float* l3b = (const float*)d_in[22];
    const float* bn3g = (const float*)d_in[23]; const float* bn3b = (const float*)d_in[24];
    const float* l4W  = (const float*)d_in[25]; const float* l4b = (const float*)d_in[26];
    float* out = (float*)d_out;

    float* ws = (float*)d_ws;
    size_t off = 0;
    float* deg = ws + off; off += NN;
    float* H   = ws + off; off += (size_t)NN * 128;
    float* agg = ws + off; off += (size_t)NN * 64;
    float* e   = ws + off; off += (size_t)NN * 64;
    float* pl  = ws + off; off += NB * 64;
    float* cnt = ws + off; off += NB;
    float* c   = ws + off; off += NB * HIDN;
    float* bv  = ws + off; off += NB * HIDN;
    float* sa  = ws + off; off += HIDN;
    float* sb  = ws + off; off += HIDN;

    (void)hipMemsetAsync(deg, 0, NN * sizeof(float), stream);
    deg_kernel<<<(NE + 255) / 256, 256, 0, stream>>>(dst, deg);
    invdeg_kernel<<<(NN + 255) / 256, 256, 0, stream>>>(deg);

    const int GB = (NN + 63) / 64;
    const int scat_blocks = (NE * 64) / 256;   // 204.8M threads / 256
    const int comb_blocks = (NN * 64 + 255) / 256;

    // conv1
    gemm_dual<DIN, true><<<GB, 256, 0, stream>>>(x, c1Wl, c1Wr, H);
    (void)hipMemsetAsync(agg, 0, (size_t)NN * 64 * sizeof(float), stream);
    scatter_kernel<<<scat_blocks, 256, 0, stream>>>(src, dst, H, agg);
    combine_kernel<<<comb_blocks, 256, 0, stream>>>(agg, deg, c1bl, H, e);

    // conv2
    gemm_dual<DH, false><<<GB, 256, 0, stream>>>(e, c2Wl, c2Wr, H);
    (void)hipMemsetAsync(agg, 0, (size_t)NN * 64 * sizeof(float), stream);
    scatter_kernel<<<scat_blocks, 256, 0, stream>>>(src, dst, H, agg);
    combine_kernel<<<comb_blocks, 256, 0, stream>>>(agg, deg, c2bl, H, e);

    // conv3
    gemm_dual<DH, false><<<GB, 256, 0, stream>>>(e, c3Wl, c3Wr, H);
    (void)hipMemsetAsync(agg, 0, (size_t)NN * 64 * sizeof(float), stream);
    scatter_kernel<<<scat_blocks, 256, 0, stream>>>(src, dst, H, agg);
    combine_kernel<<<comb_blocks, 256, 0, stream>>>(agg, deg, c3bl, H, e);

    // pool
    (void)hipMemsetAsync(pl, 0, NB * 64 * sizeof(float), stream);
    (void)hipMemsetAsync(cnt, 0, NB * sizeof(float), stream);
    pool_kernel<<<(NN * 64 + 255) / 256, 256, 0, stream>>>(e, batch, pl, cnt);
    poolfin_kernel<<<(NB * 64 + 255) / 256, 256, 0, stream>>>(pl, cnt, bv); // bv <- c0 [512,64]

    // head
    lin_kernel<<<(NB * 200 + 255) / 256, 256, 0, stream>>>(bv, l1W, l1b, c, 64, 200);
    bnstats_kernel<<<200, 256, 0, stream>>>(c, bn1g, bn1b, sa, sb, 200);
    bnapply_kernel<<<(NB * 200 + 255) / 256, 256, 0, stream>>>(c, sa, sb, bv, 200);

    lin_kernel<<<(NB * 100 + 255) / 256, 256, 0, stream>>>(bv, l2W, l2b, c, 200, 100);
    bnstats_kernel<<<100, 256, 0, stream>>>(c, bn2g, bn2b, sa, sb, 100);
    bnapply_kernel<<<(NB * 100 + 255) / 256, 256, 0, stream>>>(c, sa, sb, bv, 100);

    lin_kernel<<<(NB * 100 + 255) / 256, 256, 0, stream>>>(bv, l3W, l3b, c, 100, 100);
    bnstats_kernel<<<100, 256, 0, stream>>>(c, bn3g, bn3b, sa, sb, 100);
    bnapply_kernel<<<(NB * 100 + 255) / 256, 256, 0, stream>>>(c, sa, sb, bv, 100);

    lin_kernel<<<(NB * 80 + 255) / 256, 256, 0, stream>>>(bv, l4W, l4b, out, 100, 80);
}

// Round 4
// 1442.635 us; speedup vs baseline: 2.0365x; 2.0365x over previous
//
#include <hip/hip_runtime.h>
#include <hip/hip_bf16.h>

#define NN 100000
#define NE 3200000
#define NB 512
#define DIN 500
#define DH 64
#define HIDN 200
#define NCLS 80
#define SCAN_BS 512
#define SCAN_NBLK ((NN + SCAN_BS - 1) / SCAN_BS)   // 196

// ---------- CSR build: histogram ----------
__global__ void hist_kernel(const int* __restrict__ dst, int* __restrict__ deg_i) {
    int e = blockIdx.x * blockDim.x + threadIdx.x;
    if (e < NE) atomicAdd(&deg_i[dst[e]], 1);
}

// ---------- CSR build: per-block sums ----------
__global__ void scan1_kernel(const int* __restrict__ deg_i, int* __restrict__ bsum) {
    __shared__ int l[SCAN_BS];
    int i = blockIdx.x * SCAN_BS + threadIdx.x;
    l[threadIdx.x] = (i < NN) ? deg_i[i] : 0;
    __syncthreads();
    for (int o = SCAN_BS / 2; o > 0; o >>= 1) {
        if (threadIdx.x < o) l[threadIdx.x] += l[threadIdx.x + o];
        __syncthreads();
    }
    if (threadIdx.x == 0) bsum[blockIdx.x] = l[0];
}

// ---------- CSR build: scan block sums (serial, tiny) ----------
__global__ void scan2_kernel(int* __restrict__ bsum) {
    if (threadIdx.x == 0 && blockIdx.x == 0) {
        int s = 0;
        for (int b = 0; b < SCAN_NBLK; ++b) { int v = bsum[b]; bsum[b] = s; s += v; }
    }
}

// ---------- CSR build: exclusive scan + row_ptr/cursor/invdeg ----------
__global__ void scan3_kernel(const int* __restrict__ deg_i, const int* __restrict__ bsum,
                             int* __restrict__ row_ptr, int* __restrict__ cursor,
                             float* __restrict__ invdeg) {
    __shared__ int l[SCAN_BS];
    int i = blockIdx.x * SCAN_BS + threadIdx.x;
    int v = (i < NN) ? deg_i[i] : 0;
    l[threadIdx.x] = v;
    __syncthreads();
    for (int o = 1; o < SCAN_BS; o <<= 1) {
        int t = 0;
        if (threadIdx.x >= o) t = l[threadIdx.x - o];
        __syncthreads();
        if (threadIdx.x >= o) l[threadIdx.x] += t;
        __syncthreads();
    }
    if (i < NN) {
        int excl = l[threadIdx.x] - v + bsum[blockIdx.x];
        row_ptr[i] = excl;
        cursor[i] = excl;
        invdeg[i] = 1.0f / fmaxf((float)v, 1.0f);
        if (i == NN - 1) row_ptr[NN] = excl + v;
    }
}

// ---------- CSR build: scatter src ids ----------
__global__ void csrbuild_kernel(const int* __restrict__ src, const int* __restrict__ dst,
                                int* __restrict__ cursor, int* __restrict__ csr_src) {
    int e = blockIdx.x * blockDim.x + threadIdx.x;
    if (e < NE) {
        int p = atomicAdd(&cursor[dst[e]], 1);
        csr_src[p] = src[e];
    }
}

// ---------- dual GEMM: H[N,128] = in[N,K] @ [Wl | Wr], optional fused L1 row-scale ----------
template<int K, bool SCALE>
__launch_bounds__(256)
__global__ void gemm_dual(const float* __restrict__ in,
                          const float* __restrict__ Wl,
                          const float* __restrict__ Wr,
                          float* __restrict__ H) {
    __shared__ float x_lds[64][8];
    __shared__ float w_lds[8][128];
    __shared__ float s_lds[64];
    const int tid = threadIdx.x;
    const int row0 = blockIdx.x * 64;
    const int tc = tid & 31;
    const int tr = tid >> 5;
    const int sx_row = tid >> 2;
    const int sx_kk  = (tid & 3) * 2;
    const int sw_kk  = tid >> 5;
    const int sw_col = (tid & 31) * 4;
    const float* const Wsel = (sw_col < 64) ? Wl : Wr;
    const int swc = sw_col & 63;

    float4 acc[8];
#pragma unroll
    for (int r = 0; r < 8; ++r) acc[r] = make_float4(0.f, 0.f, 0.f, 0.f);
    float pabs = 0.f;

    const int grow = row0 + sx_row;
    const bool row_ok = grow < NN;

    for (int k0 = 0; k0 < K; k0 += 8) {
        __syncthreads();
        {
            float2 v = make_float2(0.f, 0.f);
            int gk = k0 + sx_kk;
            if (row_ok) {
                if (gk + 1 < K)      v = *(const float2*)(in + (size_t)grow * K + gk);
                else if (gk < K)     v.x = in[(size_t)grow * K + gk];
            }
            *(float2*)&x_lds[sx_row][sx_kk] = v;
            if (SCALE) pabs += fabsf(v.x) + fabsf(v.y);
        }
        {
            float4 w = make_float4(0.f, 0.f, 0.f, 0.f);
            int gk = k0 + sw_kk;
            if (gk < K) w = *(const float4*)(Wsel + (size_t)gk * 64 + swc);
            *(float4*)&w_lds[sw_kk][sw_col] = w;
        }
        __syncthreads();
#pragma unroll
        for (int h = 0; h < 2; ++h) {
            float4 wv0 = *(const float4*)&w_lds[h*4+0][tc*4];
            float4 wv1 = *(const float4*)&w_lds[h*4+1][tc*4];
            float4 wv2 = *(const float4*)&w_lds[h*4+2][tc*4];
            float4 wv3 = *(const float4*)&w_lds[h*4+3][tc*4];
#pragma unroll
            for (int r = 0; r < 8; ++r) {
                float4 xv = *(const float4*)&x_lds[tr*8+r][h*4];
                acc[r].x += xv.x*wv0.x + xv.y*wv1.x + xv.z*wv2.x + xv.w*wv3.x;
                acc[r].y += xv.x*wv0.y + xv.y*wv1.y + xv.z*wv2.y + xv.w*wv3.y;
                acc[r].z += xv.x*wv0.z + xv.y*wv1.z + xv.z*wv2.z + xv.w*wv3.z;
                acc[r].w += xv.x*wv0.w + xv.y*wv1.w + xv.z*wv2.w + xv.w*wv3.w;
            }
        }
    }

    if (SCALE) {
        __syncthreads();
        x_lds[sx_row][tid & 3] = pabs;
        __syncthreads();
        if (tid < 64) {
            float ssum = x_lds[tid][0] + x_lds[tid][1] + x_lds[tid][2] + x_lds[tid][3];
            s_lds[tid] = 1.0f / fmaxf(ssum, 1e-12f);
        }
        __syncthreads();
    }

#pragma unroll
    for (int r = 0; r < 8; ++r) {
        int gr = row0 + tr * 8 + r;
        if (gr < NN) {
            float4 o = acc[r];
            if (SCALE) {
                float sc = s_lds[tr * 8 + r];
                o.x *= sc; o.y *= sc; o.z *= sc; o.w *= sc;
            }
            *(float4*)(H + (size_t)gr * 128 + tc * 4) = o;
        }
    }
}

// ---------- CSR gather + fused combine: e = mean_{j->i} H[j,0:64]*invdeg + bl + H[i,64:128] ----------
// wave per node; 4 neighbors/iter x 16 float4-lanes
__launch_bounds__(256)
__global__ void gather_kernel(const int* __restrict__ row_ptr, const int* __restrict__ csr_src,
                              const float* __restrict__ H, const float* __restrict__ invdeg,
                              const float* __restrict__ bl, float* __restrict__ eout) {
    int node = blockIdx.x * 4 + (threadIdx.x >> 6);
    if (node >= NN) return;
    int lane = threadIdx.x & 63;
    int nb = lane >> 4;          // neighbor sub-group 0..3
    int f4 = lane & 15;          // float4 index (16 x 4 = 64 feats)
    int beg = row_ptr[node], end = row_ptr[node + 1];
    float4 acc = make_float4(0.f, 0.f, 0.f, 0.f);
    for (int p = beg + nb; p < end; p += 4) {
        int s = csr_src[p];
        const float4 v = *(const float4*)(H + (size_t)s * 128 + f4 * 4);
        acc.x += v.x; acc.y += v.y; acc.z += v.z; acc.w += v.w;
    }
    // reduce across the 4 neighbor sub-groups (lane bits 4,5)
#pragma unroll
    for (int m = 16; m < 64; m <<= 1) {
        acc.x += __shfl_xor(acc.x, m, 64);
        acc.y += __shfl_xor(acc.y, m, 64);
        acc.z += __shfl_xor(acc.z, m, 64);
        acc.w += __shfl_xor(acc.w, m, 64);
    }
    if (nb == 0) {
        float idg = invdeg[node];
        const float4 hr = *(const float4*)(H + (size_t)node * 128 + 64 + f4 * 4);
        float4 o;
        o.x = acc.x * idg + bl[f4 * 4 + 0] + hr.x;
        o.y = acc.y * idg + bl[f4 * 4 + 1] + hr.y;
        o.z = acc.z * idg + bl[f4 * 4 + 2] + hr.z;
        o.w = acc.w * idg + bl[f4 * 4 + 3] + hr.w;
        *(float4*)(eout + (size_t)node * 64 + f4 * 4) = o;
    }
}

// ---------- global mean pool ----------
__global__ void pool_kernel(const float* __restrict__ e, const int* __restrict__ batch,
                            float* __restrict__ pl, float* __restrict__ cnt) {
    int gid = blockIdx.x * blockDim.x + threadIdx.x;
    int i = gid >> 6;
    int lane = threadIdx.x & 63;
    if (i >= NN) return;
    int b = batch[i];
    atomicAdd(&pl[b * 64 + lane], e[(size_t)i * 64 + lane]);
    if (lane == 0) atomicAdd(&cnt[b], 1.0f);
}

__global__ void poolfin_kernel(const float* __restrict__ pl, const float* __restrict__ cnt,
                               float* __restrict__ c0) {
    int id = blockIdx.x * blockDim.x + threadIdx.x;
    if (id >= NB * 64) return;
    int b = id >> 6;
    c0[id] = pl[id] / fmaxf(cnt[b], 1.0f);
}

// ---------- MLP head ----------
__global__ void lin_kernel(const float* __restrict__ in, const float* __restrict__ W,
                           const float* __restrict__ bias, float* __restrict__ out,
                           int Kd, int Dout) {
    int id = blockIdx.x * blockDim.x + threadIdx.x;
    if (id >= NB * Dout) return;
    int row = id / Dout, col = id - row * Dout;
    const float* ir = in + (size_t)row * Kd;
    float acc = bias[col];
    for (int k = 0; k < Kd; ++k) acc += ir[k] * W[(size_t)k * Dout + col];
    out[id] = acc;
}

__global__ void bnstats_kernel(const float* __restrict__ c, const float* __restrict__ g,
                               const float* __restrict__ beta, float* __restrict__ sa,
                               float* __restrict__ sb, int Dout) {
    int col = blockIdx.x;
    int tid = threadIdx.x;
    float s = 0.f, sq = 0.f;
    for (int r = tid; r < NB; r += 256) {
        float v = c[(size_t)r * Dout + col];
        s += v; sq += v * v;
    }
    __shared__ float ls[256], lq[256];
    ls[tid] = s; lq[tid] = sq;
    __syncthreads();
    for (int o = 128; o > 0; o >>= 1) {
        if (tid < o) { ls[tid] += ls[tid + o]; lq[tid] += lq[tid + o]; }
        __syncthreads();
    }
    if (tid == 0) {
        float mu = ls[0] / NB;
        float var = lq[0] / NB - mu * mu;
        float a = g[col] * rsqrtf(var + 1e-5f);
        sa[col] = a;
        sb[col] = beta[col] - mu * a;
    }
}

__global__ void bnapply_kernel(const float* __restrict__ c, const float* __restrict__ sa,
                               const float* __restrict__ sb, float* __restrict__ bv, int Dout) {
    int id = blockIdx.x * blockDim.x + threadIdx.x;
    if (id >= NB * Dout) return;
    int col = id % Dout;
    bv[id] = tanhf(c[id] * sa[col] + sb[col]);
}

extern "C" void kernel_launch(void* const* d_in, const int* in_sizes, int n_in,
                              void* d_out, int out_size, void* d_ws, size_t ws_size,
                              hipStream_t stream) {
    const float* x    = (const float*)d_in[0];
    const int* ei     = (const int*)d_in[1];
    const int* src    = ei;
    const int* dst    = ei + NE;
    const int* batch  = (const int*)d_in[2];
    const float* c1Wl = (const float*)d_in[4];
    const float* c1bl = (const float*)d_in[5];
    const float* c1Wr = (const float*)d_in[6];
    const float* c2Wl = (const float*)d_in[7];
    const float* c2bl = (const float*)d_in[8];
    const float* c2Wr = (const float*)d_in[9];
    const float* c3Wl = (const float*)d_in[10];
    const float* c3bl = (const float*)d_in[11];
    const float* c3Wr = (const float*)d_in[12];
    const float* l1W  = (const float*)d_in[13]; const float* l1b = (const float*)d_in[14];
    const float* bn1g = (const float*)d_in[15]; const float* bn1b = (const float*)d_in[16];
    const float* l2W  = (const float*)d_in[17]; const float* l2b = (const float*)d_in[18];
    const float* bn2g = (const float*)d_in[19]; const float* bn2b = (const float*)d_in[20];
    const float* l3W  = (const float*)d_in[21]; const float* l3b = (const float*)d_in[22];
    const float* bn3g = (const float*)d_in[23]; const float* bn3b = (const float*)d_in[24];
    const float* l4W  = (const float*)d_in[25]; const float* l4b = (const float*)d_in[26];
    float* out = (float*)d_out;

    float* ws = (float*)d_ws;
    size_t off = 0;
    float* H      = ws + off; off += (size_t)NN * 128;
    float* e      = ws + off; off += (size_t)NN * 64;
    float* invdeg = ws + off; off += NN;
    float* pl     = ws + off; off += NB * 64;
    float* cnt    = ws + off; off += NB;
    float* c      = ws + off; off += NB * HIDN;
    float* bv     = ws + off; off += NB * HIDN;
    float* sa     = ws + off; off += HIDN;
    float* sb     = ws + off; off += HIDN;
    int* iws      = (int*)(ws + off);
    size_t ioff = 0;
    int* deg_i    = iws + ioff; ioff += NN;
    int* row_ptr  = iws + ioff; ioff += NN + 1;
    int* cursor   = iws + ioff; ioff += NN;
    int* bsum     = iws + ioff; ioff += SCAN_NBLK;
    int* csr_src  = iws + ioff; ioff += NE;

    // ---- CSR build (per launch, deterministic work) ----
    (void)hipMemsetAsync(deg_i, 0, NN * sizeof(int), stream);
    hist_kernel<<<(NE + 255) / 256, 256, 0, stream>>>(dst, deg_i);
    scan1_kernel<<<SCAN_NBLK, SCAN_BS, 0, stream>>>(deg_i, bsum);
    scan2_kernel<<<1, 64, 0, stream>>>(bsum);
    scan3_kernel<<<SCAN_NBLK, SCAN_BS, 0, stream>>>(deg_i, bsum, row_ptr, cursor, invdeg);
    csrbuild_kernel<<<(NE + 255) / 256, 256, 0, stream>>>(src, dst, cursor, csr_src);

    const int GB = (NN + 63) / 64;
    const int GGB = (NN + 3) / 4;

    // conv1
    gemm_dual<DIN, true><<<GB, 256, 0, stream>>>(x, c1Wl, c1Wr, H);
    gather_kernel<<<GGB, 256, 0, stream>>>(row_ptr, csr_src, H, invdeg, c1bl, e);
    // conv2
    gemm_dual<DH, false><<<GB, 256, 0, stream>>>(e, c2Wl, c2Wr, H);
    gather_kernel<<<GGB, 256, 0, stream>>>(row_ptr, csr_src, H, invdeg, c2bl, e);
    // conv3
    gemm_dual<DH, false><<<GB, 256, 0, stream>>>(e, c3Wl, c3Wr, H);
    gather_kernel<<<GGB, 256, 0, stream>>>(row_ptr, csr_src, H, invdeg, c3bl, e);

    // pool
    (void)hipMemsetAsync(pl, 0, NB * 64 * sizeof(float), stream);
    (void)hipMemsetAsync(cnt, 0, NB * sizeof(float), stream);
    pool_kernel<<<(NN * 64 + 255) / 256, 256, 0, stream>>>(e, batch, pl, cnt);
    poolfin_kernel<<<(NB * 64 + 255) / 256, 256, 0, stream>>>(pl, cnt, bv);

    // head
    lin_kernel<<<(NB * 200 + 255) / 256, 256, 0, stream>>>(bv, l1W, l1b, c, 64, 200);
    bnstats_kernel<<<200, 256, 0, stream>>>(c, bn1g, bn1b, sa, sb, 200);
    bnapply_kernel<<<(NB * 200 + 255) / 256, 256, 0, stream>>>(c, sa, sb, bv, 200);

    lin_kernel<<<(NB * 100 + 255) / 256, 256, 0, stream>>>(bv, l2W, l2b, c, 200, 100);
    bnstats_kernel<<<100, 256, 0, stream>>>(c, bn2g, bn2b, sa, sb, 100);
    bnapply_kernel<<<(NB * 100 + 255) / 256, 256, 0, stream>>>(c, sa, sb, bv, 100);

    lin_kernel<<<(NB * 100 + 255) / 256, 256, 0, stream>>>(bv, l3W, l3b, c, 100, 100);
    bnstats_kernel<<<100, 256, 0, stream>>>(c, bn3g, bn3b, sa, sb, 100);
    bnapply_kernel<<<(NB * 100 + 255) / 256, 256, 0, stream>>>(c, sa, sb, bv, 100);

    lin_kernel<<<(NB * 80 + 255) / 256, 256, 0, stream>>>(bv, l4W, l4b, out, 100, 80);
}

// Round 5
// 1243.735 us; speedup vs baseline: 2.3622x; 1.1599x over previous
//
#include <hip/hip_runtime.h>
#include <hip/hip_bf16.h>

#define NN 100000
#define NE 3200000
#define NB 512
#define DIN 500
#define DH 64
#define HIDN 200
#define NCLS 80
#define SCAN_BS 512
#define SCAN_NBLK ((NN + SCAN_BS - 1) / SCAN_BS)   // 196

typedef __attribute__((ext_vector_type(8))) short bf16x8;
typedef __attribute__((ext_vector_type(4))) float f32x4;

__device__ __forceinline__ short f2bf(float f) {
    union { float f; unsigned u; } v; v.f = f;
    unsigned r = v.u + 0x7FFF + ((v.u >> 16) & 1);   // RNE
    return (short)(r >> 16);
}

// ---------- CSR build: histogram ----------
__global__ void hist_kernel(const int* __restrict__ dst, int* __restrict__ deg_i) {
    int e = blockIdx.x * blockDim.x + threadIdx.x;
    if (e < NE) atomicAdd(&deg_i[dst[e]], 1);
}

// ---------- CSR build: per-block sums ----------
__global__ void scan1_kernel(const int* __restrict__ deg_i, int* __restrict__ bsum) {
    __shared__ int l[SCAN_BS];
    int i = blockIdx.x * SCAN_BS + threadIdx.x;
    l[threadIdx.x] = (i < NN) ? deg_i[i] : 0;
    __syncthreads();
    for (int o = SCAN_BS / 2; o > 0; o >>= 1) {
        if (threadIdx.x < o) l[threadIdx.x] += l[threadIdx.x + o];
        __syncthreads();
    }
    if (threadIdx.x == 0) bsum[blockIdx.x] = l[0];
}

// ---------- CSR build: scan block sums (serial, tiny) ----------
__global__ void scan2_kernel(int* __restrict__ bsum) {
    if (threadIdx.x == 0 && blockIdx.x == 0) {
        int s = 0;
        for (int b = 0; b < SCAN_NBLK; ++b) { int v = bsum[b]; bsum[b] = s; s += v; }
    }
}

// ---------- CSR build: exclusive scan + row_ptr/cursor/invdeg ----------
__global__ void scan3_kernel(const int* __restrict__ deg_i, const int* __restrict__ bsum,
                             int* __restrict__ row_ptr, int* __restrict__ cursor,
                             float* __restrict__ invdeg) {
    __shared__ int l[SCAN_BS];
    int i = blockIdx.x * SCAN_BS + threadIdx.x;
    int v = (i < NN) ? deg_i[i] : 0;
    l[threadIdx.x] = v;
    __syncthreads();
    for (int o = 1; o < SCAN_BS; o <<= 1) {
        int t = 0;
        if (threadIdx.x >= o) t = l[threadIdx.x - o];
        __syncthreads();
        if (threadIdx.x >= o) l[threadIdx.x] += t;
        __syncthreads();
    }
    if (i < NN) {
        int excl = l[threadIdx.x] - v + bsum[blockIdx.x];
        row_ptr[i] = excl;
        cursor[i] = excl;
        invdeg[i] = 1.0f / fmaxf((float)v, 1.0f);
        if (i == NN - 1) row_ptr[NN] = excl + v;
    }
}

// ---------- CSR build: scatter src ids ----------
__global__ void csrbuild_kernel(const int* __restrict__ src, const int* __restrict__ dst,
                                int* __restrict__ cursor, int* __restrict__ csr_src) {
    int e = blockIdx.x * blockDim.x + threadIdx.x;
    if (e < NE) {
        int p = atomicAdd(&cursor[dst[e]], 1);
        csr_src[p] = src[e];
    }
}

// ---------- W prep: Wb[col][k] = bf16( col<64 ? Wl[k][col] : Wr[k][col-64] ), zero-pad k>=K ----------
__global__ void wprep_kernel(const float* __restrict__ Wl, const float* __restrict__ Wr,
                             short* __restrict__ Wb, int K, int KP) {
    int id = blockIdx.x * blockDim.x + threadIdx.x;
    if (id >= 128 * KP) return;
    int col = id / KP, k = id - col * KP;
    float v = 0.f;
    if (k < K) v = (col < 64) ? Wl[(size_t)k * 64 + col] : Wr[(size_t)k * 64 + (col - 64)];
    Wb[(size_t)col * KP + k] = f2bf(v);
}

// ---------- MFMA dual GEMM: H[N,128] = bf16(in[N,K]) @ Wb, optional fused L1 row-scale ----------
// block 256 = 4 waves; tile 64 rows x 128 cols; wave w -> rows w*16..w*16+15, 8 col-frags of 16
template<int KP, int KREAL, bool SCALE>
__launch_bounds__(256)
__global__ void gemm_mfma(const float* __restrict__ in, const short* __restrict__ Wb,
                          float* __restrict__ H) {
    __shared__ short A_lds[64][40];   // [row][k], pad 32->40 (16B-aligned rows, ~2-way banks)
    __shared__ short B_lds[128][40];  // [col][k]
    __shared__ float s_red[64][4];
    const int tid = threadIdx.x;
    const int row0 = blockIdx.x * 64;
    const int w = tid >> 6, l = tid & 63;
    const int q = l >> 4, r16 = l & 15;
    // A staging coords: 4 threads/row, 8 k each
    const int sa_row = tid >> 2;
    const int sa_kc  = (tid & 3) * 8;
    const int ga_row = row0 + sa_row;
    const bool row_ok = ga_row < NN;
    const float* arow = in + (size_t)ga_row * KREAL;
    // B staging coords: 2 threads/col, 16 k each
    const int sb_col = tid >> 1;
    const int sb_kh  = (tid & 1) * 16;
    const short* bsrc = Wb + (size_t)sb_col * KP + sb_kh;

    f32x4 acc[8];
#pragma unroll
    for (int c = 0; c < 8; ++c) acc[c] = (f32x4){0.f, 0.f, 0.f, 0.f};
    float pabs = 0.f;

    for (int k0 = 0; k0 < KP; k0 += 32) {
        __syncthreads();
        { // stage A: read 8 fp32, convert, 16B LDS write
            float v[8];
            int gk = k0 + sa_kc;
#pragma unroll
            for (int i = 0; i < 8; i += 4) {
                if (row_ok && (KP == KREAL || gk + i + 3 < KREAL)) {
                    const float4 f = *(const float4*)(arow + gk + i);
                    v[i] = f.x; v[i+1] = f.y; v[i+2] = f.z; v[i+3] = f.w;
                } else {
#pragma unroll
                    for (int j = 0; j < 4; ++j)
                        v[i+j] = (row_ok && gk + i + j < KREAL) ? arow[gk + i + j] : 0.f;
                }
            }
            short s[8];
#pragma unroll
            for (int i = 0; i < 8; ++i) {
                if (SCALE) pabs += fabsf(v[i]);
                s[i] = f2bf(v[i]);
            }
            *(bf16x8*)&A_lds[sa_row][sa_kc] = *(bf16x8*)s;
        }
        { // stage B: 2 x 16B bf16 copies (coalesced global)
            *(bf16x8*)&B_lds[sb_col][sb_kh]     = *(const bf16x8*)(bsrc + k0);
            *(bf16x8*)&B_lds[sb_col][sb_kh + 8] = *(const bf16x8*)(bsrc + k0 + 8);
        }
        __syncthreads();
        bf16x8 a = *(bf16x8*)&A_lds[w * 16 + r16][q * 8];
#pragma unroll
        for (int c = 0; c < 8; ++c) {
            bf16x8 b = *(bf16x8*)&B_lds[c * 16 + r16][q * 8];
            acc[c] = __builtin_amdgcn_mfma_f32_16x16x32_bf16(a, b, acc[c], 0, 0, 0);
        }
    }

    if (SCALE) { // per-row L1 inv-norm (4 partial sums per row)
        __syncthreads();
        s_red[sa_row][tid & 3] = pabs;
        __syncthreads();
        if (tid < 64) {
            float ss = s_red[tid][0] + s_red[tid][1] + s_red[tid][2] + s_red[tid][3];
            s_red[tid][0] = 1.0f / fmaxf(ss, 1e-12f);
        }
        __syncthreads();
    }

#pragma unroll
    for (int c = 0; c < 8; ++c) {
#pragma unroll
        for (int rr = 0; rr < 4; ++rr) {
            int lrow = w * 16 + q * 4 + rr;       // C/D: col = lane&15, row = (lane>>4)*4+reg
            int grow = row0 + lrow;
            if (grow < NN) {
                float o = acc[c][rr];
                if (SCALE) o *= s_red[lrow][0];
                H[(size_t)grow * 128 + c * 16 + r16] = o;
            }
        }
    }
}

// ---------- CSR gather + fused combine (unroll x2 for MLP) ----------
__launch_bounds__(256)
__global__ void gather_kernel(const int* __restrict__ row_ptr, const int* __restrict__ csr_src,
                              const float* __restrict__ H, const float* __restrict__ invdeg,
                              const float* __restrict__ bl, float* __restrict__ eout) {
    int node = blockIdx.x * 4 + (threadIdx.x >> 6);
    if (node >= NN) return;
    int lane = threadIdx.x & 63;
    int nb = lane >> 4;
    int f4 = lane & 15;
    int beg = row_ptr[node], end = row_ptr[node + 1];
    float4 acc0 = make_float4(0.f, 0.f, 0.f, 0.f);
    float4 acc1 = make_float4(0.f, 0.f, 0.f, 0.f);
    int p = beg + nb;
    for (; p + 4 < end; p += 8) {
        int s0 = csr_src[p];
        int s1 = csr_src[p + 4];
        const float4 v0 = *(const float4*)(H + (size_t)s0 * 128 + f4 * 4);
        const float4 v1 = *(const float4*)(H + (size_t)s1 * 128 + f4 * 4);
        acc0.x += v0.x; acc0.y += v0.y; acc0.z += v0.z; acc0.w += v0.w;
        acc1.x += v1.x; acc1.y += v1.y; acc1.z += v1.z; acc1.w += v1.w;
    }
    if (p < end) {
        int s0 = csr_src[p];
        const float4 v0 = *(const float4*)(H + (size_t)s0 * 128 + f4 * 4);
        acc0.x += v0.x; acc0.y += v0.y; acc0.z += v0.z; acc0.w += v0.w;
    }
    float4 acc = make_float4(acc0.x + acc1.x, acc0.y + acc1.y, acc0.z + acc1.z, acc0.w + acc1.w);
#pragma unroll
    for (int m = 16; m < 64; m <<= 1) {
        acc.x += __shfl_xor(acc.x, m, 64);
        acc.y += __shfl_xor(acc.y, m, 64);
        acc.z += __shfl_xor(acc.z, m, 64);
        acc.w += __shfl_xor(acc.w, m, 64);
    }
    if (nb == 0) {
        float idg = invdeg[node];
        const float4 hr = *(const float4*)(H + (size_t)node * 128 + 64 + f4 * 4);
        float4 o;
        o.x = acc.x * idg + bl[f4 * 4 + 0] + hr.x;
        o.y = acc.y * idg + bl[f4 * 4 + 1] + hr.y;
        o.z = acc.z * idg + bl[f4 * 4 + 2] + hr.z;
        o.w = acc.w * idg + bl[f4 * 4 + 3] + hr.w;
        *(float4*)(eout + (size_t)node * 64 + f4 * 4) = o;
    }
}

// ---------- global mean pool ----------
__global__ void pool_kernel(const float* __restrict__ e, const int* __restrict__ batch,
                            float* __restrict__ pl, float* __restrict__ cnt) {
    int gid = blockIdx.x * blockDim.x + threadIdx.x;
    int i = gid >> 6;
    int lane = threadIdx.x & 63;
    if (i >= NN) return;
    int b = batch[i];
    atomicAdd(&pl[b * 64 + lane], e[(size_t)i * 64 + lane]);
    if (lane == 0) atomicAdd(&cnt[b], 1.0f);
}

__global__ void poolfin_kernel(const float* __restrict__ pl, const float* __restrict__ cnt,
                               float* __restrict__ c0) {
    int id = blockIdx.x * blockDim.x + threadIdx.x;
    if (id >= NB * 64) return;
    int b = id >> 6;
    c0[id] = pl[id] / fmaxf(cnt[b], 1.0f);
}

// ---------- MLP head ----------
__global__ void lin_kernel(const float* __restrict__ in, const float* __restrict__ W,
                           const float* __restrict__ bias, float* __restrict__ out,
                           int Kd, int Dout) {
    int id = blockIdx.x * blockDim.x + threadIdx.x;
    if (id >= NB * Dout) return;
    int row = id / Dout, col = id - row * Dout;
    const float* ir = in + (size_t)row * Kd;
    float acc = bias[col];
    for (int k = 0; k < Kd; ++k) acc += ir[k] * W[(size_t)k * Dout + col];
    out[id] = acc;
}

__global__ void bnstats_kernel(const float* __restrict__ c, const float* __restrict__ g,
                               const float* __restrict__ beta, float* __restrict__ sa,
                               float* __restrict__ sb, int Dout) {
    int col = blockIdx.x;
    int tid = threadIdx.x;
    float s = 0.f, sq = 0.f;
    for (int r = tid; r < NB; r += 256) {
        float v = c[(size_t)r * Dout + col];
        s += v; sq += v * v;
    }
    __shared__ float ls[256], lq[256];
    ls[tid] = s; lq[tid] = sq;
    __syncthreads();
    for (int o = 128; o > 0; o >>= 1) {
        if (tid < o) { ls[tid] += ls[tid + o]; lq[tid] += lq[tid + o]; }
        __syncthreads();
    }
    if (tid == 0) {
        float mu = ls[0] / NB;
        float var = lq[0] / NB - mu * mu;
        float a = g[col] * rsqrtf(var + 1e-5f);
        sa[col] = a;
        sb[col] = beta[col] - mu * a;
    }
}

__global__ void bnapply_kernel(const float* __restrict__ c, const float* __restrict__ sa,
                               const float* __restrict__ sb, float* __restrict__ bv, int Dout) {
    int id = blockIdx.x * blockDim.x + threadIdx.x;
    if (id >= NB * Dout) return;
    int col = id % Dout;
    bv[id] = tanhf(c[id] * sa[col] + sb[col]);
}

extern "C" void kernel_launch(void* const* d_in, const int* in_sizes, int n_in,
                              void* d_out, int out_size, void* d_ws, size_t ws_size,
                              hipStream_t stream) {
    const float* x    = (const float*)d_in[0];
    const int* ei     = (const int*)d_in[1];
    const int* src    = ei;
    const int* dst    = ei + NE;
    const int* batch  = (const int*)d_in[2];
    const float* c1Wl = (const float*)d_in[4];
    const float* c1bl = (const float*)d_in[5];
    const float* c1Wr = (const float*)d_in[6];
    const float* c2Wl = (const float*)d_in[7];
    const float* c2bl = (const float*)d_in[8];
    const float* c2Wr = (const float*)d_in[9];
    const float* c3Wl = (const float*)d_in[10];
    const float* c3bl = (const float*)d_in[11];
    const float* c3Wr = (const float*)d_in[12];
    const float* l1W  = (const float*)d_in[13]; const float* l1b = (const float*)d_in[14];
    const float* bn1g = (const float*)d_in[15]; const float* bn1b = (const float*)d_in[16];
    const float* l2W  = (const float*)d_in[17]; const float* l2b = (const float*)d_in[18];
    const float* bn2g = (const float*)d_in[19]; const float* bn2b = (const float*)d_in[20];
    const float* l3W  = (const float*)d_in[21]; const float* l3b = (const float*)d_in[22];
    const float* bn3g = (const float*)d_in[23]; const float* bn3b = (const float*)d_in[24];
    const float* l4W  = (const float*)d_in[25]; const float* l4b = (const float*)d_in[26];
    float* out = (float*)d_out;

    float* ws = (float*)d_ws;
    size_t off = 0;
    float* H      = ws + off; off += (size_t)NN * 128;
    float* e      = ws + off; off += (size_t)NN * 64;
    float* invdeg = ws + off; off += NN;
    float* pl     = ws + off; off += NB * 64;
    float* cnt    = ws + off; off += NB;
    float* c      = ws + off; off += NB * HIDN;
    float* bv     = ws + off; off += NB * HIDN;
    float* sa     = ws + off; off += HIDN;
    float* sb     = ws + off; off += HIDN;
    short* Wb1    = (short*)(ws + off); off += 128 * 512 / 2;   // bf16 [128][512]
    short* Wb2    = (short*)(ws + off); off += 128 * 64 / 2;    // bf16 [128][64]
    short* Wb3    = (short*)(ws + off); off += 128 * 64 / 2;
    int* iws      = (int*)(ws + off);
    size_t ioff = 0;
    int* deg_i    = iws + ioff; ioff += NN;
    int* row_ptr  = iws + ioff; ioff += NN + 1;
    int* cursor   = iws + ioff; ioff += NN;
    int* bsum     = iws + ioff; ioff += SCAN_NBLK;
    int* csr_src  = iws + ioff; ioff += NE;

    // ---- CSR build (per launch, deterministic work) ----
    (void)hipMemsetAsync(deg_i, 0, NN * sizeof(int), stream);
    hist_kernel<<<(NE + 255) / 256, 256, 0, stream>>>(dst, deg_i);
    scan1_kernel<<<SCAN_NBLK, SCAN_BS, 0, stream>>>(deg_i, bsum);
    scan2_kernel<<<1, 64, 0, stream>>>(bsum);
    scan3_kernel<<<SCAN_NBLK, SCAN_BS, 0, stream>>>(deg_i, bsum, row_ptr, cursor, invdeg);
    csrbuild_kernel<<<(NE + 255) / 256, 256, 0, stream>>>(src, dst, cursor, csr_src);

    // ---- weight prep (bf16, col-major, zero-padded K) ----
    wprep_kernel<<<(128 * 512 + 255) / 256, 256, 0, stream>>>(c1Wl, c1Wr, Wb1, DIN, 512);
    wprep_kernel<<<(128 * 64 + 255) / 256, 256, 0, stream>>>(c2Wl, c2Wr, Wb2, DH, 64);
    wprep_kernel<<<(128 * 64 + 255) / 256, 256, 0, stream>>>(c3Wl, c3Wr, Wb3, DH, 64);

    const int GB = (NN + 63) / 64;
    const int GGB = (NN + 3) / 4;

    // conv1
    gemm_mfma<512, DIN, true><<<GB, 256, 0, stream>>>(x, Wb1, H);
    gather_kernel<<<GGB, 256, 0, stream>>>(row_ptr, csr_src, H, invdeg, c1bl, e);
    // conv2
    gemm_mfma<64, DH, false><<<GB, 256, 0, stream>>>(e, Wb2, H);
    gather_kernel<<<GGB, 256, 0, stream>>>(row_ptr, csr_src, H, invdeg, c2bl, e);
    // conv3
    gemm_mfma<64, DH, false><<<GB, 256, 0, stream>>>(e, Wb3, H);
    gather_kernel<<<GGB, 256, 0, stream>>>(row_ptr, csr_src, H, invdeg, c3bl, e);

    // pool
    (void)hipMemsetAsync(pl, 0, NB * 64 * sizeof(float), stream);
    (void)hipMemsetAsync(cnt, 0, NB * sizeof(float), stream);
    pool_kernel<<<(NN * 64 + 255) / 256, 256, 0, stream>>>(e, batch, pl, cnt);
    poolfin_kernel<<<(NB * 64 + 255) / 256, 256, 0, stream>>>(pl, cnt, bv);

    // head
    lin_kernel<<<(NB * 200 + 255) / 256, 256, 0, stream>>>(bv, l1W, l1b, c, 64, 200);
    bnstats_kernel<<<200, 256, 0, stream>>>(c, bn1g, bn1b, sa, sb, 200);
    bnapply_kernel<<<(NB * 200 + 255) / 256, 256, 0, stream>>>(c, sa, sb, bv, 200);

    lin_kernel<<<(NB * 100 + 255) / 256, 256, 0, stream>>>(bv, l2W, l2b, c, 200, 100);
    bnstats_kernel<<<100, 256, 0, stream>>>(c, bn2g, bn2b, sa, sb, 100);
    bnapply_kernel<<<(NB * 100 + 255) / 256, 256, 0, stream>>>(c, sa, sb, bv, 100);

    lin_kernel<<<(NB * 100 + 255) / 256, 256, 0, stream>>>(bv, l3W, l3b, c, 100, 100);
    bnstats_kernel<<<100, 256, 0, stream>>>(c, bn3g, bn3b, sa, sb, 100);
    bnapply_kernel<<<(NB * 100 + 255) / 256, 256, 0, stream>>>(c, sa, sb, bv, 100);

    lin_kernel<<<(NB * 80 + 255) / 256, 256, 0, stream>>>(bv, l4W, l4b, out, 100, 80);
}

// Round 6
// 923.197 us; speedup vs baseline: 3.1824x; 1.3472x over previous
//
#include <hip/hip_runtime.h>
#include <hip/hip_bf16.h>

#define NN 100000
#define NE 3200000
#define NB 512
#define DIN 500
#define DH 64
#define HIDN 200
#define NCLS 80

#define NBUK 256                 // buckets for CSR counting sort
#define NPB 391                  // nodes per bucket (256*391 >= 100000)
#define EPB 16384                // edges per block in bucket passes
#define NBLK_E ((NE + EPB - 1) / EPB)   // 196

typedef __attribute__((ext_vector_type(8))) short bf16x8;
typedef __attribute__((ext_vector_type(4))) float f32x4;

__device__ __forceinline__ short f2bf(float f) {
    union { float f; unsigned u; } v; v.f = f;
    unsigned r = v.u + 0x7FFF + ((v.u >> 16) & 1);   // RNE
    return (short)(r >> 16);
}

// ---------- CSR pass A: per-block bucket histogram ----------
__global__ void bukhist_kernel(const int* __restrict__ dst, int* __restrict__ block_hist) {
    __shared__ int h[NBUK];
    for (int i = threadIdx.x; i < NBUK; i += 256) h[i] = 0;
    __syncthreads();
    int base = blockIdx.x * EPB;
    int end = min(base + EPB, NE);
    for (int e = base + threadIdx.x; e < end; e += 256)
        atomicAdd(&h[dst[e] / NPB], 1);
    __syncthreads();
    for (int i = threadIdx.x; i < NBUK; i += 256)
        block_hist[blockIdx.x * NBUK + i] = h[i];
}

// ---------- CSR pass B: (block,bucket) write bases + bucket bases (1 block of 256) ----------
__global__ void bukoff_kernel(int* __restrict__ block_hist, int* __restrict__ buk_base) {
    __shared__ int tot[NBUK];
    __shared__ int sc[NBUK];
    int b = threadIdx.x;
    int s = 0;
    for (int i = 0; i < NBLK_E; ++i) s += block_hist[i * NBUK + b];
    tot[b] = s; sc[b] = s;
    __syncthreads();
    for (int o = 1; o < NBUK; o <<= 1) {
        int t = (b >= o) ? sc[b - o] : 0;
        __syncthreads();
        sc[b] += t;
        __syncthreads();
    }
    int excl = sc[b] - tot[b];
    buk_base[b] = excl;
    if (b == NBUK - 1) buk_base[NBUK] = excl + tot[b];
    int run = excl;
    for (int i = 0; i < NBLK_E; ++i) {
        int idx = i * NBUK + b;
        int v = block_hist[idx];
        block_hist[idx] = run;
        run += v;
    }
}

// ---------- CSR pass C: scatter packed (src<<9 | local_dst) into bucket runs ----------
__global__ void bukscat_kernel(const int* __restrict__ src, const int* __restrict__ dst,
                               const int* __restrict__ block_hist, int* __restrict__ bpack) {
    __shared__ int cur[NBUK];
    for (int i = threadIdx.x; i < NBUK; i += 256)
        cur[i] = block_hist[blockIdx.x * NBUK + i];
    __syncthreads();
    int base = blockIdx.x * EPB;
    int end = min(base + EPB, NE);
    for (int e = base + threadIdx.x; e < end; e += 256) {
        int d = dst[e];
        int bk = d / NPB;
        int p = atomicAdd(&cur[bk], 1);
        bpack[p] = (src[e] << 9) | (d - bk * NPB);
    }
}

// ---------- CSR pass D: per-bucket row_ptr / invdeg / csr_src ----------
__global__ void bukfin_kernel(const int* __restrict__ buk_base, const int* __restrict__ bpack,
                              int* __restrict__ row_ptr, float* __restrict__ invdeg,
                              int* __restrict__ csr_src) {
    __shared__ int cnt[NPB];
    __shared__ int cbase[NPB];
    int bk = blockIdx.x;
    int n0 = bk * NPB;
    int nloc = min(n0 + NPB, NN) - n0;
    for (int i = threadIdx.x; i < nloc; i += 256) cnt[i] = 0;
    __syncthreads();
    int beg = buk_base[bk], end = buk_base[bk + 1];
    for (int p = beg + threadIdx.x; p < end; p += 256)
        atomicAdd(&cnt[bpack[p] & 511], 1);
    __syncthreads();
    if (threadIdx.x == 0) {
        int run = beg;
        for (int i = 0; i < nloc; ++i) { int v = cnt[i]; cbase[i] = run; run += v; }
    }
    __syncthreads();
    for (int i = threadIdx.x; i < nloc; i += 256) {
        row_ptr[n0 + i] = cbase[i];
        invdeg[n0 + i] = 1.0f / fmaxf((float)cnt[i], 1.0f);
        cnt[i] = cbase[i];   // reuse as cursor
    }
    if (bk == NBUK - 1 && threadIdx.x == 0) row_ptr[NN] = end;
    __syncthreads();
    for (int p = beg + threadIdx.x; p < end; p += 256) {
        int v = bpack[p];
        int q = atomicAdd(&cnt[v & 511], 1);
        csr_src[q] = v >> 9;
    }
}

// ---------- W prep: Wb[col][k] = bf16( col<64 ? Wl[k][col] : Wr[k][col-64] ), zero-pad k>=K ----------
__global__ void wprep_kernel(const float* __restrict__ Wl, const float* __restrict__ Wr,
                             short* __restrict__ Wb, int K, int KP) {
    int id = blockIdx.x * blockDim.x + threadIdx.x;
    if (id >= 128 * KP) return;
    int col = id / KP, k = id - col * KP;
    float v = 0.f;
    if (k < K) v = (col < 64) ? Wl[(size_t)k * 64 + col] : Wr[(size_t)k * 64 + (col - 64)];
    Wb[(size_t)col * KP + k] = f2bf(v);
}

// ---------- MFMA dual GEMM: H[N,128] = bf16(in[N,K]) @ Wb, optional fused L1 row-scale ----------
template<int KP, int KREAL, bool SCALE>
__launch_bounds__(256)
__global__ void gemm_mfma(const float* __restrict__ in, const short* __restrict__ Wb,
                          float* __restrict__ H) {
    __shared__ short A_lds[64][40];
    __shared__ short B_lds[128][40];
    __shared__ float s_red[64][4];
    const int tid = threadIdx.x;
    const int row0 = blockIdx.x * 64;
    const int w = tid >> 6, l = tid & 63;
    const int q = l >> 4, r16 = l & 15;
    const int sa_row = tid >> 2;
    const int sa_kc  = (tid & 3) * 8;
    const int ga_row = row0 + sa_row;
    const bool row_ok = ga_row < NN;
    const float* arow = in + (size_t)ga_row * KREAL;
    const int sb_col = tid >> 1;
    const int sb_kh  = (tid & 1) * 16;
    const short* bsrc = Wb + (size_t)sb_col * KP + sb_kh;

    f32x4 acc[8];
#pragma unroll
    for (int c = 0; c < 8; ++c) acc[c] = (f32x4){0.f, 0.f, 0.f, 0.f};
    float pabs = 0.f;

    for (int k0 = 0; k0 < KP; k0 += 32) {
        __syncthreads();
        {
            float v[8];
            int gk = k0 + sa_kc;
#pragma unroll
            for (int i = 0; i < 8; i += 4) {
                if (row_ok && (KP == KREAL || gk + i + 3 < KREAL)) {
                    const float4 f = *(const float4*)(arow + gk + i);
                    v[i] = f.x; v[i+1] = f.y; v[i+2] = f.z; v[i+3] = f.w;
                } else {
#pragma unroll
                    for (int j = 0; j < 4; ++j)
                        v[i+j] = (row_ok && gk + i + j < KREAL) ? arow[gk + i + j] : 0.f;
                }
            }
            short s[8];
#pragma unroll
            for (int i = 0; i < 8; ++i) {
                if (SCALE) pabs += fabsf(v[i]);
                s[i] = f2bf(v[i]);
            }
            *(bf16x8*)&A_lds[sa_row][sa_kc] = *(bf16x8*)s;
        }
        {
            *(bf16x8*)&B_lds[sb_col][sb_kh]     = *(const bf16x8*)(bsrc + k0);
            *(bf16x8*)&B_lds[sb_col][sb_kh + 8] = *(const bf16x8*)(bsrc + k0 + 8);
        }
        __syncthreads();
        bf16x8 a = *(bf16x8*)&A_lds[w * 16 + r16][q * 8];
#pragma unroll
        for (int c = 0; c < 8; ++c) {
            bf16x8 b = *(bf16x8*)&B_lds[c * 16 + r16][q * 8];
            acc[c] = __builtin_amdgcn_mfma_f32_16x16x32_bf16(a, b, acc[c], 0, 0, 0);
        }
    }

    if (SCALE) {
        __syncthreads();
        s_red[sa_row][tid & 3] = pabs;
        __syncthreads();
        if (tid < 64) {
            float ss = s_red[tid][0] + s_red[tid][1] + s_red[tid][2] + s_red[tid][3];
            s_red[tid][0] = 1.0f / fmaxf(ss, 1e-12f);
        }
        __syncthreads();
    }

#pragma unroll
    for (int c = 0; c < 8; ++c) {
#pragma unroll
        for (int rr = 0; rr < 4; ++rr) {
            int lrow = w * 16 + q * 4 + rr;
            int grow = row0 + lrow;
            if (grow < NN) {
                float o = acc[c][rr];
                if (SCALE) o *= s_red[lrow][0];
                H[(size_t)grow * 128 + c * 16 + r16] = o;
            }
        }
    }
}

// ---------- CSR gather + fused combine (unroll x2) ----------
__launch_bounds__(256)
__global__ void gather_kernel(const int* __restrict__ row_ptr, const int* __restrict__ csr_src,
                              const float* __restrict__ H, const float* __restrict__ invdeg,
                              const float* __restrict__ bl, float* __restrict__ eout) {
    int node = blockIdx.x * 4 + (threadIdx.x >> 6);
    if (node >= NN) return;
    int lane = threadIdx.x & 63;
    int nb = lane >> 4;
    int f4 = lane & 15;
    int beg = row_ptr[node], end = row_ptr[node + 1];
    float4 acc0 = make_float4(0.f, 0.f, 0.f, 0.f);
    float4 acc1 = make_float4(0.f, 0.f, 0.f, 0.f);
    int p = beg + nb;
    for (; p + 4 < end; p += 8) {
        int s0 = csr_src[p];
        int s1 = csr_src[p + 4];
        const float4 v0 = *(const float4*)(H + (size_t)s0 * 128 + f4 * 4);
        const float4 v1 = *(const float4*)(H + (size_t)s1 * 128 + f4 * 4);
        acc0.x += v0.x; acc0.y += v0.y; acc0.z += v0.z; acc0.w += v0.w;
        acc1.x += v1.x; acc1.y += v1.y; acc1.z += v1.z; acc1.w += v1.w;
    }
    if (p < end) {
        int s0 = csr_src[p];
        const float4 v0 = *(const float4*)(H + (size_t)s0 * 128 + f4 * 4);
        acc0.x += v0.x; acc0.y += v0.y; acc0.z += v0.z; acc0.w += v0.w;
    }
    float4 acc = make_float4(acc0.x + acc1.x, acc0.y + acc1.y, acc0.z + acc1.z, acc0.w + acc1.w);
#pragma unroll
    for (int m = 16; m < 64; m <<= 1) {
        acc.x += __shfl_xor(acc.x, m, 64);
        acc.y += __shfl_xor(acc.y, m, 64);
        acc.z += __shfl_xor(acc.z, m, 64);
        acc.w += __shfl_xor(acc.w, m, 64);
    }
    if (nb == 0) {
        float idg = invdeg[node];
        const float4 hr = *(const float4*)(H + (size_t)node * 128 + 64 + f4 * 4);
        float4 o;
        o.x = acc.x * idg + bl[f4 * 4 + 0] + hr.x;
        o.y = acc.y * idg + bl[f4 * 4 + 1] + hr.y;
        o.z = acc.z * idg + bl[f4 * 4 + 2] + hr.z;
        o.w = acc.w * idg + bl[f4 * 4 + 3] + hr.w;
        *(float4*)(eout + (size_t)node * 64 + f4 * 4) = o;
    }
}

// ---------- global mean pool ----------
__global__ void pool_kernel(const float* __restrict__ e, const int* __restrict__ batch,
                            float* __restrict__ pl, float* __restrict__ cnt) {
    int gid = blockIdx.x * blockDim.x + threadIdx.x;
    int i = gid >> 6;
    int lane = threadIdx.x & 63;
    if (i >= NN) return;
    int b = batch[i];
    atomicAdd(&pl[b * 64 + lane], e[(size_t)i * 64 + lane]);
    if (lane == 0) atomicAdd(&cnt[b], 1.0f);
}

__global__ void poolfin_kernel(const float* __restrict__ pl, const float* __restrict__ cnt,
                               float* __restrict__ c0) {
    int id = blockIdx.x * blockDim.x + threadIdx.x;
    if (id >= NB * 64) return;
    int b = id >> 6;
    c0[id] = pl[id] / fmaxf(cnt[b], 1.0f);
}

// ---------- MLP head ----------
__global__ void lin_kernel(const float* __restrict__ in, const float* __restrict__ W,
                           const float* __restrict__ bias, float* __restrict__ out,
                           int Kd, int Dout) {
    int id = blockIdx.x * blockDim.x + threadIdx.x;
    if (id >= NB * Dout) return;
    int row = id / Dout, col = id - row * Dout;
    const float* ir = in + (size_t)row * Kd;
    float acc = bias[col];
    for (int k = 0; k < Kd; ++k) acc += ir[k] * W[(size_t)k * Dout + col];
    out[id] = acc;
}

__global__ void bnstats_kernel(const float* __restrict__ c, const float* __restrict__ g,
                               const float* __restrict__ beta, float* __restrict__ sa,
                               float* __restrict__ sb, int Dout) {
    int col = blockIdx.x;
    int tid = threadIdx.x;
    float s = 0.f, sq = 0.f;
    for (int r = tid; r < NB; r += 256) {
        float v = c[(size_t)r * Dout + col];
        s += v; sq += v * v;
    }
    __shared__ float ls[256], lq[256];
    ls[tid] = s; lq[tid] = sq;
    __syncthreads();
    for (int o = 128; o > 0; o >>= 1) {
        if (tid < o) { ls[tid] += ls[tid + o]; lq[tid] += lq[tid + o]; }
        __syncthreads();
    }
    if (tid == 0) {
        float mu = ls[0] / NB;
        float var = lq[0] / NB - mu * mu;
        float a = g[col] * rsqrtf(var + 1e-5f);
        sa[col] = a;
        sb[col] = beta[col] - mu * a;
    }
}

__global__ void bnapply_kernel(const float* __restrict__ c, const float* __restrict__ sa,
                               const float* __restrict__ sb, float* __restrict__ bv, int Dout) {
    int id = blockIdx.x * blockDim.x + threadIdx.x;
    if (id >= NB * Dout) return;
    int col = id % Dout;
    bv[id] = tanhf(c[id] * sa[col] + sb[col]);
}

extern "C" void kernel_launch(void* const* d_in, const int* in_sizes, int n_in,
                              void* d_out, int out_size, void* d_ws, size_t ws_size,
                              hipStream_t stream) {
    const float* x    = (const float*)d_in[0];
    const int* ei     = (const int*)d_in[1];
    const int* src    = ei;
    const int* dst    = ei + NE;
    const int* batch  = (const int*)d_in[2];
    const float* c1Wl = (const float*)d_in[4];
    const float* c1bl = (const float*)d_in[5];
    const float* c1Wr = (const float*)d_in[6];
    const float* c2Wl = (const float*)d_in[7];
    const float* c2bl = (const float*)d_in[8];
    const float* c2Wr = (const float*)d_in[9];
    const float* c3Wl = (const float*)d_in[10];
    const float* c3bl = (const float*)d_in[11];
    const float* c3Wr = (const float*)d_in[12];
    const float* l1W  = (const float*)d_in[13]; const float* l1b = (const float*)d_in[14];
    const float* bn1g = (const float*)d_in[15]; const float* bn1b = (const float*)d_in[16];
    const float* l2W  = (const float*)d_in[17]; const float* l2b = (const float*)d_in[18];
    const float* bn2g = (const float*)d_in[19]; const float* bn2b = (const float*)d_in[20];
    const float* l3W  = (const float*)d_in[21]; const float* l3b = (const float*)d_in[22];
    const float* bn3g = (const float*)d_in[23]; const float* bn3b = (const float*)d_in[24];
    const float* l4W  = (const float*)d_in[25]; const float* l4b = (const float*)d_in[26];
    float* out = (float*)d_out;

    float* ws = (float*)d_ws;
    size_t off = 0;
    float* H      = ws + off; off += (size_t)NN * 128;
    float* e      = ws + off; off += (size_t)NN * 64;
    float* invdeg = ws + off; off += NN;
    float* pl     = ws + off; off += NB * 64;
    float* cnt    = ws + off; off += NB;
    float* c      = ws + off; off += NB * HIDN;
    float* bv     = ws + off; off += NB * HIDN;
    float* sa     = ws + off; off += HIDN;
    float* sb     = ws + off; off += HIDN;
    short* Wb1    = (short*)(ws + off); off += 128 * 512 / 2;
    short* Wb2    = (short*)(ws + off); off += 128 * 64 / 2;
    short* Wb3    = (short*)(ws + off); off += 128 * 64 / 2;
    int* iws      = (int*)(ws + off);
    size_t ioff = 0;
    int* row_ptr  = iws + ioff; ioff += NN + 1;
    int* csr_src  = iws + ioff; ioff += NE;
    int* buk_base = iws + ioff; ioff += NBUK + 1;
    // scratch aliased into buffers that are dead during CSR build:
    int* bpack      = (int*)H;   // NE ints, dead before gemm1 writes H
    int* block_hist = (int*)e;   // NBLK_E*NBUK ints, dead before gather1 writes e

    // ---- CSR build: bucketed counting sort (no write amplification) ----
    bukhist_kernel<<<NBLK_E, 256, 0, stream>>>(dst, block_hist);
    bukoff_kernel<<<1, NBUK, 0, stream>>>(block_hist, buk_base);
    bukscat_kernel<<<NBLK_E, 256, 0, stream>>>(src, dst, block_hist, bpack);
    bukfin_kernel<<<NBUK, 256, 0, stream>>>(buk_base, bpack, row_ptr, invdeg, csr_src);

    // ---- weight prep (bf16, col-major, zero-padded K) ----
    wprep_kernel<<<(128 * 512 + 255) / 256, 256, 0, stream>>>(c1Wl, c1Wr, Wb1, DIN, 512);
    wprep_kernel<<<(128 * 64 + 255) / 256, 256, 0, stream>>>(c2Wl, c2Wr, Wb2, DH, 64);
    wprep_kernel<<<(128 * 64 + 255) / 256, 256, 0, stream>>>(c3Wl, c3Wr, Wb3, DH, 64);

    const int GB = (NN + 63) / 64;
    const int GGB = (NN + 3) / 4;

    // conv1
    gemm_mfma<512, DIN, true><<<GB, 256, 0, stream>>>(x, Wb1, H);
    gather_kernel<<<GGB, 256, 0, stream>>>(row_ptr, csr_src, H, invdeg, c1bl, e);
    // conv2
    gemm_mfma<64, DH, false><<<GB, 256, 0, stream>>>(e, Wb2, H);
    gather_kernel<<<GGB, 256, 0, stream>>>(row_ptr, csr_src, H, invdeg, c2bl, e);
    // conv3
    gemm_mfma<64, DH, false><<<GB, 256, 0, stream>>>(e, Wb3, H);
    gather_kernel<<<GGB, 256, 0, stream>>>(row_ptr, csr_src, H, invdeg, c3bl, e);

    // pool
    (void)hipMemsetAsync(pl, 0, NB * 64 * sizeof(float), stream);
    (void)hipMemsetAsync(cnt, 0, NB * sizeof(float), stream);
    pool_kernel<<<(NN * 64 + 255) / 256, 256, 0, stream>>>(e, batch, pl, cnt);
    poolfin_kernel<<<(NB * 64 + 255) / 256, 256, 0, stream>>>(pl, cnt, bv);

    // head
    lin_kernel<<<(NB * 200 + 255) / 256, 256, 0, stream>>>(bv, l1W, l1b, c, 64, 200);
    bnstats_kernel<<<200, 256, 0, stream>>>(c, bn1g, bn1b, sa, sb, 200);
    bnapply_kernel<<<(NB * 200 + 255) / 256, 256, 0, stream>>>(c, sa, sb, bv, 200);

    lin_kernel<<<(NB * 100 + 255) / 256, 256, 0, stream>>>(bv, l2W, l2b, c, 200, 100);
    bnstats_kernel<<<100, 256, 0, stream>>>(c, bn2g, bn2b, sa, sb, 100);
    bnapply_kernel<<<(NB * 100 + 255) / 256, 256, 0, stream>>>(c, sa, sb, bv, 100);

    lin_kernel<<<(NB * 100 + 255) / 256, 256, 0, stream>>>(bv, l3W, l3b, c, 100, 100);
    bnstats_kernel<<<100, 256, 0, stream>>>(c, bn3g, bn3b, sa, sb, 100);
    bnapply_kernel<<<(NB * 100 + 255) / 256, 256, 0, stream>>>(c, sa, sb, bv, 100);

    lin_kernel<<<(NB * 80 + 255) / 256, 256, 0, stream>>>(bv, l4W, l4b, out, 100, 80);
}

// Round 7
// 736.995 us; speedup vs baseline: 3.9864x; 1.2527x over previous
//
#include <hip/hip_runtime.h>
#include <hip/hip_bf16.h>

#define NN 100000
#define NE 3200000
#define NB 512
#define DIN 500
#define DH 64
#define HIDN 200
#define NCLS 80

#define NBUK 256                 // buckets for CSR counting sort
#define NPB 391                  // nodes per bucket (256*391 >= 100000)
#define EPB 16384                // edges per block in bucket passes
#define NBLK_E ((NE + EPB - 1) / EPB)   // 196

typedef __attribute__((ext_vector_type(8))) short bf16x8;
typedef __attribute__((ext_vector_type(4))) float f32x4;

__device__ __forceinline__ short f2bf(float f) {
    union { float f; unsigned u; } v; v.f = f;
    unsigned r = v.u + 0x7FFF + ((v.u >> 16) & 1);   // RNE
    return (short)(r >> 16);
}

// ---------- CSR pass A: per-block bucket histogram ----------
__global__ void bukhist_kernel(const int* __restrict__ dst, int* __restrict__ block_hist) {
    __shared__ int h[NBUK];
    for (int i = threadIdx.x; i < NBUK; i += 256) h[i] = 0;
    __syncthreads();
    int base = blockIdx.x * EPB;
    int end = min(base + EPB, NE);
    for (int e = base + threadIdx.x; e < end; e += 256)
        atomicAdd(&h[dst[e] / NPB], 1);
    __syncthreads();
    for (int i = threadIdx.x; i < NBUK; i += 256)
        block_hist[blockIdx.x * NBUK + i] = h[i];
}

// ---------- CSR pass B: (block,bucket) write bases + bucket bases (1 block of 256) ----------
__global__ void bukoff_kernel(int* __restrict__ block_hist, int* __restrict__ buk_base) {
    __shared__ int tot[NBUK];
    __shared__ int sc[NBUK];
    int b = threadIdx.x;
    int s = 0;
    for (int i = 0; i < NBLK_E; ++i) s += block_hist[i * NBUK + b];
    tot[b] = s; sc[b] = s;
    __syncthreads();
    for (int o = 1; o < NBUK; o <<= 1) {
        int t = (b >= o) ? sc[b - o] : 0;
        __syncthreads();
        sc[b] += t;
        __syncthreads();
    }
    int excl = sc[b] - tot[b];
    buk_base[b] = excl;
    if (b == NBUK - 1) buk_base[NBUK] = excl + tot[b];
    int run = excl;
    for (int i = 0; i < NBLK_E; ++i) {
        int idx = i * NBUK + b;
        int v = block_hist[idx];
        block_hist[idx] = run;
        run += v;
    }
}

// ---------- CSR pass C: scatter packed (src<<9 | local_dst) into bucket runs ----------
__global__ void bukscat_kernel(const int* __restrict__ src, const int* __restrict__ dst,
                               const int* __restrict__ block_hist, int* __restrict__ bpack) {
    __shared__ int cur[NBUK];
    for (int i = threadIdx.x; i < NBUK; i += 256)
        cur[i] = block_hist[blockIdx.x * NBUK + i];
    __syncthreads();
    int base = blockIdx.x * EPB;
    int end = min(base + EPB, NE);
    for (int e = base + threadIdx.x; e < end; e += 256) {
        int d = dst[e];
        int bk = d / NPB;
        int p = atomicAdd(&cur[bk], 1);
        bpack[p] = (src[e] << 9) | (d - bk * NPB);
    }
}

// ---------- CSR pass D: per-bucket row_ptr / invdeg / csr_src ----------
__global__ void bukfin_kernel(const int* __restrict__ buk_base, const int* __restrict__ bpack,
                              int* __restrict__ row_ptr, float* __restrict__ invdeg,
                              int* __restrict__ csr_src) {
    __shared__ int cnt[NPB];
    __shared__ int cbase[NPB];
    int bk = blockIdx.x;
    int n0 = bk * NPB;
    int nloc = min(n0 + NPB, NN) - n0;
    for (int i = threadIdx.x; i < nloc; i += 256) cnt[i] = 0;
    __syncthreads();
    int beg = buk_base[bk], end = buk_base[bk + 1];
    for (int p = beg + threadIdx.x; p < end; p += 256)
        atomicAdd(&cnt[bpack[p] & 511], 1);
    __syncthreads();
    if (threadIdx.x == 0) {
        int run = beg;
        for (int i = 0; i < nloc; ++i) { int v = cnt[i]; cbase[i] = run; run += v; }
    }
    __syncthreads();
    for (int i = threadIdx.x; i < nloc; i += 256) {
        row_ptr[n0 + i] = cbase[i];
        invdeg[n0 + i] = 1.0f / fmaxf((float)cnt[i], 1.0f);
        cnt[i] = cbase[i];   // reuse as cursor
    }
    if (bk == NBUK - 1 && threadIdx.x == 0) row_ptr[NN] = end;
    __syncthreads();
    for (int p = beg + threadIdx.x; p < end; p += 256) {
        int v = bpack[p];
        int q = atomicAdd(&cnt[v & 511], 1);
        csr_src[q] = v >> 9;
    }
}

// ---------- W prep ----------
__global__ void wprep_kernel(const float* __restrict__ Wl, const float* __restrict__ Wr,
                             short* __restrict__ Wb, int K, int KP) {
    int id = blockIdx.x * blockDim.x + threadIdx.x;
    if (id >= 128 * KP) return;
    int col = id / KP, k = id - col * KP;
    float v = 0.f;
    if (k < K) v = (col < 64) ? Wl[(size_t)k * 64 + col] : Wr[(size_t)k * 64 + (col - 64)];
    Wb[(size_t)col * KP + k] = f2bf(v);
}

// ---------- MFMA dual GEMM ----------
template<int KP, int KREAL, bool SCALE>
__launch_bounds__(256)
__global__ void gemm_mfma(const float* __restrict__ in, const short* __restrict__ Wb,
                          float* __restrict__ H) {
    __shared__ short A_lds[64][40];
    __shared__ short B_lds[128][40];
    __shared__ float s_red[64][4];
    const int tid = threadIdx.x;
    const int row0 = blockIdx.x * 64;
    const int w = tid >> 6, l = tid & 63;
    const int q = l >> 4, r16 = l & 15;
    const int sa_row = tid >> 2;
    const int sa_kc  = (tid & 3) * 8;
    const int ga_row = row0 + sa_row;
    const bool row_ok = ga_row < NN;
    const float* arow = in + (size_t)ga_row * KREAL;
    const int sb_col = tid >> 1;
    const int sb_kh  = (tid & 1) * 16;
    const short* bsrc = Wb + (size_t)sb_col * KP + sb_kh;

    f32x4 acc[8];
#pragma unroll
    for (int c = 0; c < 8; ++c) acc[c] = (f32x4){0.f, 0.f, 0.f, 0.f};
    float pabs = 0.f;

    for (int k0 = 0; k0 < KP; k0 += 32) {
        __syncthreads();
        {
            float v[8];
            int gk = k0 + sa_kc;
#pragma unroll
            for (int i = 0; i < 8; i += 4) {
                if (row_ok && (KP == KREAL || gk + i + 3 < KREAL)) {
                    const float4 f = *(const float4*)(arow + gk + i);
                    v[i] = f.x; v[i+1] = f.y; v[i+2] = f.z; v[i+3] = f.w;
                } else {
#pragma unroll
                    for (int j = 0; j < 4; ++j)
                        v[i+j] = (row_ok && gk + i + j < KREAL) ? arow[gk + i + j] : 0.f;
                }
            }
            short s[8];
#pragma unroll
            for (int i = 0; i < 8; ++i) {
                if (SCALE) pabs += fabsf(v[i]);
                s[i] = f2bf(v[i]);
            }
            *(bf16x8*)&A_lds[sa_row][sa_kc] = *(bf16x8*)s;
        }
        {
            *(bf16x8*)&B_lds[sb_col][sb_kh]     = *(const bf16x8*)(bsrc + k0);
            *(bf16x8*)&B_lds[sb_col][sb_kh + 8] = *(const bf16x8*)(bsrc + k0 + 8);
        }
        __syncthreads();
        bf16x8 a = *(bf16x8*)&A_lds[w * 16 + r16][q * 8];
#pragma unroll
        for (int c = 0; c < 8; ++c) {
            bf16x8 b = *(bf16x8*)&B_lds[c * 16 + r16][q * 8];
            acc[c] = __builtin_amdgcn_mfma_f32_16x16x32_bf16(a, b, acc[c], 0, 0, 0);
        }
    }

    if (SCALE) {
        __syncthreads();
        s_red[sa_row][tid & 3] = pabs;
        __syncthreads();
        if (tid < 64) {
            float ss = s_red[tid][0] + s_red[tid][1] + s_red[tid][2] + s_red[tid][3];
            s_red[tid][0] = 1.0f / fmaxf(ss, 1e-12f);
        }
        __syncthreads();
    }

#pragma unroll
    for (int c = 0; c < 8; ++c) {
#pragma unroll
        for (int rr = 0; rr < 4; ++rr) {
            int lrow = w * 16 + q * 4 + rr;
            int grow = row0 + lrow;
            if (grow < NN) {
                float o = acc[c][rr];
                if (SCALE) o *= s_red[lrow][0];
                H[(size_t)grow * 128 + c * 16 + r16] = o;
            }
        }
    }
}

// ---------- CSR gather + fused combine (unroll x2) ----------
__launch_bounds__(256)
__global__ void gather_kernel(const int* __restrict__ row_ptr, const int* __restrict__ csr_src,
                              const float* __restrict__ H, const float* __restrict__ invdeg,
                              const float* __restrict__ bl, float* __restrict__ eout) {
    int node = blockIdx.x * 4 + (threadIdx.x >> 6);
    if (node >= NN) return;
    int lane = threadIdx.x & 63;
    int nb = lane >> 4;
    int f4 = lane & 15;
    int beg = row_ptr[node], end = row_ptr[node + 1];
    float4 acc0 = make_float4(0.f, 0.f, 0.f, 0.f);
    float4 acc1 = make_float4(0.f, 0.f, 0.f, 0.f);
    int p = beg + nb;
    for (; p + 4 < end; p += 8) {
        int s0 = csr_src[p];
        int s1 = csr_src[p + 4];
        const float4 v0 = *(const float4*)(H + (size_t)s0 * 128 + f4 * 4);
        const float4 v1 = *(const float4*)(H + (size_t)s1 * 128 + f4 * 4);
        acc0.x += v0.x; acc0.y += v0.y; acc0.z += v0.z; acc0.w += v0.w;
        acc1.x += v1.x; acc1.y += v1.y; acc1.z += v1.z; acc1.w += v1.w;
    }
    if (p < end) {
        int s0 = csr_src[p];
        const float4 v0 = *(const float4*)(H + (size_t)s0 * 128 + f4 * 4);
        acc0.x += v0.x; acc0.y += v0.y; acc0.z += v0.z; acc0.w += v0.w;
    }
    float4 acc = make_float4(acc0.x + acc1.x, acc0.y + acc1.y, acc0.z + acc1.z, acc0.w + acc1.w);
#pragma unroll
    for (int m = 16; m < 64; m <<= 1) {
        acc.x += __shfl_xor(acc.x, m, 64);
        acc.y += __shfl_xor(acc.y, m, 64);
        acc.z += __shfl_xor(acc.z, m, 64);
        acc.w += __shfl_xor(acc.w, m, 64);
    }
    if (nb == 0) {
        float idg = invdeg[node];
        const float4 hr = *(const float4*)(H + (size_t)node * 128 + 64 + f4 * 4);
        float4 o;
        o.x = acc.x * idg + bl[f4 * 4 + 0] + hr.x;
        o.y = acc.y * idg + bl[f4 * 4 + 1] + hr.y;
        o.z = acc.z * idg + bl[f4 * 4 + 2] + hr.z;
        o.w = acc.w * idg + bl[f4 * 4 + 3] + hr.w;
        *(float4*)(eout + (size_t)node * 64 + f4 * 4) = o;
    }
}

// ---------- pool: segment starts from sorted batch ----------
__global__ void gseg_kernel(const int* __restrict__ batch, int* __restrict__ gstart) {
    int i = blockIdx.x * blockDim.x + threadIdx.x;
    if (i >= NN) return;
    int bc = batch[i];
    int bp = (i == 0) ? -1 : batch[i - 1];
    for (int b = bp + 1; b <= bc; ++b) gstart[b] = i;
    if (i == NN - 1)
        for (int b = bc + 1; b <= NB; ++b) gstart[b] = NN;
}

// ---------- pool: segmented mean, one block (4 waves) per graph, no atomics ----------
__launch_bounds__(256)
__global__ void pool_seg(const float* __restrict__ e, const int* __restrict__ gstart,
                         float* __restrict__ c0) {
    __shared__ float part[4][64];
    int b = blockIdx.x;
    int w = threadIdx.x >> 6, lane = threadIdx.x & 63;
    int s = gstart[b], t = gstart[b + 1];
    float acc = 0.f;
    for (int i = s + w; i < t; i += 4) acc += e[(size_t)i * 64 + lane];
    part[w][lane] = acc;
    __syncthreads();
    if (w == 0) {
        float v = part[0][lane] + part[1][lane] + part[2][lane] + part[3][lane];
        c0[b * 64 + lane] = v / fmaxf((float)(t - s), 1.0f);
    }
}

// ---------- MLP head ----------
__global__ void lin_kernel(const float* __restrict__ in, const float* __restrict__ W,
                           const float* __restrict__ bias, float* __restrict__ out,
                           int Kd, int Dout) {
    int id = blockIdx.x * blockDim.x + threadIdx.x;
    if (id >= NB * Dout) return;
    int row = id / Dout, col = id - row * Dout;
    const float* ir = in + (size_t)row * Kd;
    float acc = bias[col];
    for (int k = 0; k < Kd; ++k) acc += ir[k] * W[(size_t)k * Dout + col];
    out[id] = acc;
}

__global__ void bnstats_kernel(const float* __restrict__ c, const float* __restrict__ g,
                               const float* __restrict__ beta, float* __restrict__ sa,
                               float* __restrict__ sb, int Dout) {
    int col = blockIdx.x;
    int tid = threadIdx.x;
    float s = 0.f, sq = 0.f;
    for (int r = tid; r < NB; r += 256) {
        float v = c[(size_t)r * Dout + col];
        s += v; sq += v * v;
    }
    __shared__ float ls[256], lq[256];
    ls[tid] = s; lq[tid] = sq;
    __syncthreads();
    for (int o = 128; o > 0; o >>= 1) {
        if (tid < o) { ls[tid] += ls[tid + o]; lq[tid] += lq[tid + o]; }
        __syncthreads();
    }
    if (tid == 0) {
        float mu = ls[0] / NB;
        float var = lq[0] / NB - mu * mu;
        float a = g[col] * rsqrtf(var + 1e-5f);
        sa[col] = a;
        sb[col] = beta[col] - mu * a;
    }
}

__global__ void bnapply_kernel(const float* __restrict__ c, const float* __restrict__ sa,
                               const float* __restrict__ sb, float* __restrict__ bv, int Dout) {
    int id = blockIdx.x * blockDim.x + threadIdx.x;
    if (id >= NB * Dout) return;
    int col = id % Dout;
    bv[id] = tanhf(c[id] * sa[col] + sb[col]);
}

extern "C" void kernel_launch(void* const* d_in, const int* in_sizes, int n_in,
                              void* d_out, int out_size, void* d_ws, size_t ws_size,
                              hipStream_t stream) {
    const float* x    = (const float*)d_in[0];
    const int* ei     = (const int*)d_in[1];
    const int* src    = ei;
    const int* dst    = ei + NE;
    const int* batch  = (const int*)d_in[2];
    const float* c1Wl = (const float*)d_in[4];
    const float* c1bl = (const float*)d_in[5];
    const float* c1Wr = (const float*)d_in[6];
    const float* c2Wl = (const float*)d_in[7];
    const float* c2bl = (const float*)d_in[8];
    const float* c2Wr = (const float*)d_in[9];
    const float* c3Wl = (const float*)d_in[10];
    const float* c3bl = (const float*)d_in[11];
    const float* c3Wr = (const float*)d_in[12];
    const float* l1W  = (const float*)d_in[13]; const float* l1b = (const float*)d_in[14];
    const float* bn1g = (const float*)d_in[15]; const float* bn1b = (const float*)d_in[16];
    const float* l2W  = (const float*)d_in[17]; const float* l2b = (const float*)d_in[18];
    const float* bn2g = (const float*)d_in[19]; const float* bn2b = (const float*)d_in[20];
    const float* l3W  = (const float*)d_in[21]; const float* l3b = (const float*)d_in[22];
    const float* bn3g = (const float*)d_in[23]; const float* bn3b = (const float*)d_in[24];
    const float* l4W  = (const float*)d_in[25]; const float* l4b = (const float*)d_in[26];
    float* out = (float*)d_out;

    float* ws = (float*)d_ws;
    size_t off = 0;
    float* H      = ws + off; off += (size_t)NN * 128;
    float* e      = ws + off; off += (size_t)NN * 64;
    float* invdeg = ws + off; off += NN;
    float* c      = ws + off; off += NB * HIDN;
    float* bv     = ws + off; off += NB * HIDN;
    float* sa     = ws + off; off += HIDN;
    float* sb     = ws + off; off += HIDN;
    short* Wb1    = (short*)(ws + off); off += 128 * 512 / 2;
    short* Wb2    = (short*)(ws + off); off += 128 * 64 / 2;
    short* Wb3    = (short*)(ws + off); off += 128 * 64 / 2;
    int* iws      = (int*)(ws + off);
    size_t ioff = 0;
    int* row_ptr  = iws + ioff; ioff += NN + 1;
    int* csr_src  = iws + ioff; ioff += NE;
    int* buk_base = iws + ioff; ioff += NBUK + 1;
    int* gstart   = iws + ioff; ioff += NB + 1;
    // scratch aliased into buffers that are dead during CSR build:
    int* bpack      = (int*)H;   // NE ints, dead before gemm1 writes H
    int* block_hist = (int*)e;   // NBLK_E*NBUK ints, dead before gather1 writes e

    // ---- CSR build: bucketed counting sort ----
    bukhist_kernel<<<NBLK_E, 256, 0, stream>>>(dst, block_hist);
    bukoff_kernel<<<1, NBUK, 0, stream>>>(block_hist, buk_base);
    bukscat_kernel<<<NBLK_E, 256, 0, stream>>>(src, dst, block_hist, bpack);
    bukfin_kernel<<<NBUK, 256, 0, stream>>>(buk_base, bpack, row_ptr, invdeg, csr_src);

    // ---- graph segment table (batch is sorted) ----
    gseg_kernel<<<(NN + 255) / 256, 256, 0, stream>>>(batch, gstart);

    // ---- weight prep ----
    wprep_kernel<<<(128 * 512 + 255) / 256, 256, 0, stream>>>(c1Wl, c1Wr, Wb1, DIN, 512);
    wprep_kernel<<<(128 * 64 + 255) / 256, 256, 0, stream>>>(c2Wl, c2Wr, Wb2, DH, 64);
    wprep_kernel<<<(128 * 64 + 255) / 256, 256, 0, stream>>>(c3Wl, c3Wr, Wb3, DH, 64);

    const int GB = (NN + 63) / 64;
    const int GGB = (NN + 3) / 4;

    // conv1
    gemm_mfma<512, DIN, true><<<GB, 256, 0, stream>>>(x, Wb1, H);
    gather_kernel<<<GGB, 256, 0, stream>>>(row_ptr, csr_src, H, invdeg, c1bl, e);
    // conv2
    gemm_mfma<64, DH, false><<<GB, 256, 0, stream>>>(e, Wb2, H);
    gather_kernel<<<GGB, 256, 0, stream>>>(row_ptr, csr_src, H, invdeg, c2bl, e);
    // conv3
    gemm_mfma<64, DH, false><<<GB, 256, 0, stream>>>(e, Wb3, H);
    gather_kernel<<<GGB, 256, 0, stream>>>(row_ptr, csr_src, H, invdeg, c3bl, e);

    // pool (segmented, no atomics) -> bv holds c0 [512,64]
    pool_seg<<<NB, 256, 0, stream>>>(e, gstart, bv);

    // head
    lin_kernel<<<(NB * 200 + 255) / 256, 256, 0, stream>>>(bv, l1W, l1b, c, 64, 200);
    bnstats_kernel<<<200, 256, 0, stream>>>(c, bn1g, bn1b, sa, sb, 200);
    bnapply_kernel<<<(NB * 200 + 255) / 256, 256, 0, stream>>>(c, sa, sb, bv, 200);

    lin_kernel<<<(NB * 100 + 255) / 256, 256, 0, stream>>>(bv, l2W, l2b, c, 200, 100);
    bnstats_kernel<<<100, 256, 0, stream>>>(c, bn2g, bn2b, sa, sb, 100);
    bnapply_kernel<<<(NB * 100 + 255) / 256, 256, 0, stream>>>(c, sa, sb, bv, 100);

    lin_kernel<<<(NB * 100 + 255) / 256, 256, 0, stream>>>(bv, l3W, l3b, c, 100, 100);
    bnstats_kernel<<<100, 256, 0, stream>>>(c, bn3g, bn3b, sa, sb, 100);
    bnapply_kernel<<<(NB * 100 + 255) / 256, 256, 0, stream>>>(c, sa, sb, bv, 100);

    lin_kernel<<<(NB * 80 + 255) / 256, 256, 0, stream>>>(bv, l4W, l4b, out, 100, 80);
}

// Round 8
// 575.796 us; speedup vs baseline: 5.1025x; 1.2800x over previous
//
#include <hip/hip_runtime.h>
#include <hip/hip_bf16.h>

#define NN 100000
#define NE 3200000
#define NB 512
#define DIN 500
#define DH 64
#define HIDN 200
#define NCLS 80

#define NBUK 256
#define NPB 391
#define EPB 16384
#define NBLK_E ((NE + EPB - 1) / EPB)   // 196

typedef __attribute__((ext_vector_type(8))) short bf16x8;
typedef __attribute__((ext_vector_type(4))) float f32x4;

__device__ __forceinline__ short f2bf(float f) {
    union { float f; unsigned u; } v; v.f = f;
    unsigned r = v.u + 0x7FFF + ((v.u >> 16) & 1);   // RNE
    return (short)(r >> 16);
}
__device__ __forceinline__ float bf2f(short s) {
    union { unsigned u; float f; } v; v.u = ((unsigned)(unsigned short)s) << 16;
    return v.f;
}

// ---------- CSR pass A: per-block bucket histogram ----------
__global__ void bukhist_kernel(const int* __restrict__ dst, int* __restrict__ block_hist) {
    __shared__ int h[NBUK];
    for (int i = threadIdx.x; i < NBUK; i += 256) h[i] = 0;
    __syncthreads();
    int base = blockIdx.x * EPB;
    int end = min(base + EPB, NE);
    for (int e = base + threadIdx.x; e < end; e += 256)
        atomicAdd(&h[dst[e] / NPB], 1);
    __syncthreads();
    for (int i = threadIdx.x; i < NBUK; i += 256)
        block_hist[blockIdx.x * NBUK + i] = h[i];
}

// ---------- CSR pass B ----------
__global__ void bukoff_kernel(int* __restrict__ block_hist, int* __restrict__ buk_base) {
    __shared__ int tot[NBUK];
    __shared__ int sc[NBUK];
    int b = threadIdx.x;
    int s = 0;
    for (int i = 0; i < NBLK_E; ++i) s += block_hist[i * NBUK + b];
    tot[b] = s; sc[b] = s;
    __syncthreads();
    for (int o = 1; o < NBUK; o <<= 1) {
        int t = (b >= o) ? sc[b - o] : 0;
        __syncthreads();
        sc[b] += t;
        __syncthreads();
    }
    int excl = sc[b] - tot[b];
    buk_base[b] = excl;
    if (b == NBUK - 1) buk_base[NBUK] = excl + tot[b];
    int run = excl;
    for (int i = 0; i < NBLK_E; ++i) {
        int idx = i * NBUK + b;
        int v = block_hist[idx];
        block_hist[idx] = run;
        run += v;
    }
}

// ---------- CSR pass C ----------
__global__ void bukscat_kernel(const int* __restrict__ src, const int* __restrict__ dst,
                               const int* __restrict__ block_hist, int* __restrict__ bpack) {
    __shared__ int cur[NBUK];
    for (int i = threadIdx.x; i < NBUK; i += 256)
        cur[i] = block_hist[blockIdx.x * NBUK + i];
    __syncthreads();
    int base = blockIdx.x * EPB;
    int end = min(base + EPB, NE);
    for (int e = base + threadIdx.x; e < end; e += 256) {
        int d = dst[e];
        int bk = d / NPB;
        int p = atomicAdd(&cur[bk], 1);
        bpack[p] = (src[e] << 9) | (d - bk * NPB);
    }
}

// ---------- CSR pass D ----------
__global__ void bukfin_kernel(const int* __restrict__ buk_base, const int* __restrict__ bpack,
                              int* __restrict__ row_ptr, float* __restrict__ invdeg,
                              int* __restrict__ csr_src) {
    __shared__ int cnt[NPB];
    __shared__ int cbase[NPB];
    int bk = blockIdx.x;
    int n0 = bk * NPB;
    int nloc = min(n0 + NPB, NN) - n0;
    for (int i = threadIdx.x; i < nloc; i += 256) cnt[i] = 0;
    __syncthreads();
    int beg = buk_base[bk], end = buk_base[bk + 1];
    for (int p = beg + threadIdx.x; p < end; p += 256)
        atomicAdd(&cnt[bpack[p] & 511], 1);
    __syncthreads();
    if (threadIdx.x == 0) {
        int run = beg;
        for (int i = 0; i < nloc; ++i) { int v = cnt[i]; cbase[i] = run; run += v; }
    }
    __syncthreads();
    for (int i = threadIdx.x; i < nloc; i += 256) {
        row_ptr[n0 + i] = cbase[i];
        invdeg[n0 + i] = 1.0f / fmaxf((float)cnt[i], 1.0f);
        cnt[i] = cbase[i];
    }
    if (bk == NBUK - 1 && threadIdx.x == 0) row_ptr[NN] = end;
    __syncthreads();
    for (int p = beg + threadIdx.x; p < end; p += 256) {
        int v = bpack[p];
        int q = atomicAdd(&cnt[v & 511], 1);
        csr_src[q] = v >> 9;
    }
}

// ---------- W prep: Wb[col][k] bf16, zero-pad k>=K ----------
__global__ void wprep_kernel(const float* __restrict__ Wl, const float* __restrict__ Wr,
                             short* __restrict__ Wb, int K, int KP) {
    int id = blockIdx.x * blockDim.x + threadIdx.x;
    if (id >= 128 * KP) return;
    int col = id / KP, k = id - col * KP;
    float v = 0.f;
    if (k < K) v = (col < 64) ? Wl[(size_t)k * 64 + col] : Wr[(size_t)k * 64 + (col - 64)];
    Wb[(size_t)col * KP + k] = f2bf(v);
}

// ---------- conv1: pipelined MFMA GEMM (fp32 in, L1-scale fused, bf16 Hl/Hr out) ----------
// 64 rows x 128 cols per block; double-buffered LDS, reg-staged prefetch, 1 barrier/K-step
template<int KP, int KREAL, bool SCALE>
__launch_bounds__(256)
__global__ void gemm_mfma_pipe(const float* __restrict__ in, const short* __restrict__ Wb,
                               short* __restrict__ Hl, short* __restrict__ Hr) {
    __shared__ short A_lds[2][64][40];
    __shared__ short B_lds[2][128][40];
    __shared__ float s_red[64][4];
    const int tid = threadIdx.x;
    const int row0 = blockIdx.x * 64;
    const int w = tid >> 6, l = tid & 63;
    const int q = l >> 4, r16 = l & 15;
    const int sa_row = tid >> 2;
    const int sa_kc  = (tid & 3) * 8;
    const int ga_row = row0 + sa_row;
    const bool row_ok = ga_row < NN;
    const float* arow = in + (size_t)ga_row * KREAL;
    const int sb_col = tid >> 1;
    const int sb_kh  = (tid & 1) * 16;
    const short* bsrc = Wb + (size_t)sb_col * KP + sb_kh;

    f32x4 acc[8];
#pragma unroll
    for (int c = 0; c < 8; ++c) acc[c] = (f32x4){0.f, 0.f, 0.f, 0.f};
    float pabs = 0.f;
    float va[8];
    bf16x8 vb0, vb1;
    constexpr int NT = KP / 32;

    auto loadA = [&](int t) {
        int gk = t * 32 + sa_kc;
#pragma unroll
        for (int i = 0; i < 8; i += 4) {
            if (row_ok && (KP == KREAL || gk + i + 3 < KREAL)) {
                const float4 f = *(const float4*)(arow + gk + i);
                va[i] = f.x; va[i + 1] = f.y; va[i + 2] = f.z; va[i + 3] = f.w;
            } else {
#pragma unroll
                for (int j = 0; j < 4; ++j)
                    va[i + j] = (row_ok && gk + i + j < KREAL) ? arow[gk + i + j] : 0.f;
            }
        }
    };
    auto loadB = [&](int t) {
        vb0 = *(const bf16x8*)(bsrc + t * 32);
        vb1 = *(const bf16x8*)(bsrc + t * 32 + 8);
    };
    auto store = [&](int buf) {
        short s[8];
#pragma unroll
        for (int i = 0; i < 8; ++i) {
            if (SCALE) pabs += fabsf(va[i]);
            s[i] = f2bf(va[i]);
        }
        *(bf16x8*)&A_lds[buf][sa_row][sa_kc] = *(bf16x8*)s;
        *(bf16x8*)&B_lds[buf][sb_col][sb_kh] = vb0;
        *(bf16x8*)&B_lds[buf][sb_col][sb_kh + 8] = vb1;
    };

    loadA(0); loadB(0);
    store(0);
    __syncthreads();
    int cur = 0;
    for (int t = 0; t < NT; ++t) {
        if (t + 1 < NT) { loadA(t + 1); loadB(t + 1); }   // prefetch overlaps MFMAs below
        bf16x8 a = *(bf16x8*)&A_lds[cur][w * 16 + r16][q * 8];
#pragma unroll
        for (int c = 0; c < 8; ++c) {
            bf16x8 b = *(bf16x8*)&B_lds[cur][c * 16 + r16][q * 8];
            acc[c] = __builtin_amdgcn_mfma_f32_16x16x32_bf16(a, b, acc[c], 0, 0, 0);
        }
        if (t + 1 < NT) {
            store(cur ^ 1);      // waits vmcnt here, after MFMAs issued
            __syncthreads();     // single barrier per K-step
            cur ^= 1;
        }
    }

    if (SCALE) {
        __syncthreads();
        s_red[sa_row][tid & 3] = pabs;
        __syncthreads();
        if (tid < 64) {
            float ss = s_red[tid][0] + s_red[tid][1] + s_red[tid][2] + s_red[tid][3];
            s_red[tid][0] = 1.0f / fmaxf(ss, 1e-12f);
        }
        __syncthreads();
    }

#pragma unroll
    for (int c = 0; c < 8; ++c) {
#pragma unroll
        for (int rr = 0; rr < 4; ++rr) {
            int lrow = w * 16 + q * 4 + rr;
            int grow = row0 + lrow;
            if (grow < NN) {
                float o = acc[c][rr];
                if (SCALE) o *= s_red[lrow][0];
                short ob = f2bf(o);
                if (c < 4) Hl[(size_t)grow * 64 + c * 16 + r16] = ob;
                else       Hr[(size_t)grow * 64 + (c - 4) * 16 + r16] = ob;
            }
        }
    }
}

// ---------- conv2/3: barrier-free MFMA GEMM, K=64, bf16 in (direct global frags) ----------
__launch_bounds__(256)
__global__ void gemm64_mfma(const short* __restrict__ ein, const short* __restrict__ Wb,
                            short* __restrict__ Hl, short* __restrict__ Hr) {
    const int tid = threadIdx.x;
    const int row0 = blockIdx.x * 64;
    const int w = tid >> 6, l = tid & 63;
    const int q = l >> 4, r16 = l & 15;
    const int arow = row0 + w * 16 + r16;
    const bool ok = arow < NN;
    const short* ap = ein + (size_t)(ok ? arow : 0) * 64 + q * 8;
    f32x4 acc[8];
#pragma unroll
    for (int c = 0; c < 8; ++c) acc[c] = (f32x4){0.f, 0.f, 0.f, 0.f};
    const bf16x8 z8 = (bf16x8){0, 0, 0, 0, 0, 0, 0, 0};
#pragma unroll
    for (int t = 0; t < 2; ++t) {
        bf16x8 a = ok ? *(const bf16x8*)(ap + t * 32) : z8;
#pragma unroll
        for (int c = 0; c < 8; ++c) {
            bf16x8 b = *(const bf16x8*)(Wb + (size_t)(c * 16 + r16) * 64 + t * 32 + q * 8);
            acc[c] = __builtin_amdgcn_mfma_f32_16x16x32_bf16(a, b, acc[c], 0, 0, 0);
        }
    }
#pragma unroll
    for (int c = 0; c < 8; ++c) {
#pragma unroll
        for (int rr = 0; rr < 4; ++rr) {
            int grow = row0 + w * 16 + q * 4 + rr;
            if (grow < NN) {
                short ob = f2bf(acc[c][rr]);
                if (c < 4) Hl[(size_t)grow * 64 + c * 16 + r16] = ob;
                else       Hr[(size_t)grow * 64 + (c - 4) * 16 + r16] = ob;
            }
        }
    }
}

// ---------- CSR gather + fused combine: bf16 Hl/Hr -> bf16 e ----------
// wave per node: 8 neighbor-groups x 8 lanes (bf16x8 = 8 feats each), unroll x2
__launch_bounds__(256)
__global__ void gather_kernel(const int* __restrict__ row_ptr, const int* __restrict__ csr_src,
                              const short* __restrict__ Hl, const short* __restrict__ Hr,
                              const float* __restrict__ invdeg, const float* __restrict__ bl,
                              short* __restrict__ eout) {
    int node = blockIdx.x * 4 + (threadIdx.x >> 6);
    if (node >= NN) return;
    int lane = threadIdx.x & 63;
    int ng = lane >> 3;          // neighbor sub-group 0..7
    int fl = lane & 7;           // bf16x8 index (8 x 8 = 64 feats)
    int beg = row_ptr[node], end = row_ptr[node + 1];
    float a0[8], a1[8];
#pragma unroll
    for (int j = 0; j < 8; ++j) { a0[j] = 0.f; a1[j] = 0.f; }
    int p = beg + ng;
    for (; p + 8 < end; p += 16) {
        int s0 = csr_src[p];
        int s1 = csr_src[p + 8];
        bf16x8 v0 = *(const bf16x8*)(Hl + (size_t)s0 * 64 + fl * 8);
        bf16x8 v1 = *(const bf16x8*)(Hl + (size_t)s1 * 64 + fl * 8);
#pragma unroll
        for (int j = 0; j < 8; ++j) { a0[j] += bf2f(v0[j]); a1[j] += bf2f(v1[j]); }
    }
    if (p < end) {
        int s0 = csr_src[p];
        bf16x8 v0 = *(const bf16x8*)(Hl + (size_t)s0 * 64 + fl * 8);
#pragma unroll
        for (int j = 0; j < 8; ++j) a0[j] += bf2f(v0[j]);
    }
#pragma unroll
    for (int j = 0; j < 8; ++j) a0[j] += a1[j];
#pragma unroll
    for (int m = 8; m < 64; m <<= 1)
#pragma unroll
        for (int j = 0; j < 8; ++j) a0[j] += __shfl_xor(a0[j], m, 64);
    if (ng == 0) {
        float idg = invdeg[node];
        bf16x8 hr = *(const bf16x8*)(Hr + (size_t)node * 64 + fl * 8);
        short o[8];
#pragma unroll
        for (int j = 0; j < 8; ++j)
            o[j] = f2bf(a0[j] * idg + bl[fl * 8 + j] + bf2f(hr[j]));
        *(bf16x8*)(eout + (size_t)node * 64 + fl * 8) = *(bf16x8*)o;
    }
}

// ---------- pool: segment starts from sorted batch ----------
__global__ void gseg_kernel(const int* __restrict__ batch, int* __restrict__ gstart) {
    int i = blockIdx.x * blockDim.x + threadIdx.x;
    if (i >= NN) return;
    int bc = batch[i];
    int bp = (i == 0) ? -1 : batch[i - 1];
    for (int b = bp + 1; b <= bc; ++b) gstart[b] = i;
    if (i == NN - 1)
        for (int b = bc + 1; b <= NB; ++b) gstart[b] = NN;
}

// ---------- pool: segmented mean over bf16 e, no atomics ----------
__launch_bounds__(256)
__global__ void pool_seg(const short* __restrict__ e, const int* __restrict__ gstart,
                         float* __restrict__ c0) {
    __shared__ float part[4][64];
    int b = blockIdx.x;
    int w = threadIdx.x >> 6, lane = threadIdx.x & 63;
    int s = gstart[b], t = gstart[b + 1];
    float acc = 0.f;
    for (int i = s + w; i < t; i += 4) acc += bf2f(e[(size_t)i * 64 + lane]);
    part[w][lane] = acc;
    __syncthreads();
    if (w == 0) {
        float v = part[0][lane] + part[1][lane] + part[2][lane] + part[3][lane];
        c0[b * 64 + lane] = v / fmaxf((float)(t - s), 1.0f);
    }
}

// ---------- MLP head ----------
__global__ void lin_kernel(const float* __restrict__ in, const float* __restrict__ W,
                           const float* __restrict__ bias, float* __restrict__ out,
                           int Kd, int Dout) {
    int id = blockIdx.x * blockDim.x + threadIdx.x;
    if (id >= NB * Dout) return;
    int row = id / Dout, col = id - row * Dout;
    const float* ir = in + (size_t)row * Kd;
    float acc = bias[col];
    for (int k = 0; k < Kd; ++k) acc += ir[k] * W[(size_t)k * Dout + col];
    out[id] = acc;
}

__global__ void bnstats_kernel(const float* __restrict__ c, const float* __restrict__ g,
                               const float* __restrict__ beta, float* __restrict__ sa,
                               float* __restrict__ sb, int Dout) {
    int col = blockIdx.x;
    int tid = threadIdx.x;
    float s = 0.f, sq = 0.f;
    for (int r = tid; r < NB; r += 256) {
        float v = c[(size_t)r * Dout + col];
        s += v; sq += v * v;
    }
    __shared__ float ls[256], lq[256];
    ls[tid] = s; lq[tid] = sq;
    __syncthreads();
    for (int o = 128; o > 0; o >>= 1) {
        if (tid < o) { ls[tid] += ls[tid + o]; lq[tid] += lq[tid + o]; }
        __syncthreads();
    }
    if (tid == 0) {
        float mu = ls[0] / NB;
        float var = lq[0] / NB - mu * mu;
        float a = g[col] * rsqrtf(var + 1e-5f);
        sa[col] = a;
        sb[col] = beta[col] - mu * a;
    }
}

__global__ void bnapply_kernel(const float* __restrict__ c, const float* __restrict__ sa,
                               const float* __restrict__ sb, float* __restrict__ bv, int Dout) {
    int id = blockIdx.x * blockDim.x + threadIdx.x;
    if (id >= NB * Dout) return;
    int col = id % Dout;
    bv[id] = tanhf(c[id] * sa[col] + sb[col]);
}

extern "C" void kernel_launch(void* const* d_in, const int* in_sizes, int n_in,
                              void* d_out, int out_size, void* d_ws, size_t ws_size,
                              hipStream_t stream) {
    const float* x    = (const float*)d_in[0];
    const int* ei     = (const int*)d_in[1];
    const int* src    = ei;
    const int* dst    = ei + NE;
    const int* batch  = (const int*)d_in[2];
    const float* c1Wl = (const float*)d_in[4];
    const float* c1bl = (const float*)d_in[5];
    const float* c1Wr = (const float*)d_in[6];
    const float* c2Wl = (const float*)d_in[7];
    const float* c2bl = (const float*)d_in[8];
    const float* c2Wr = (const float*)d_in[9];
    const float* c3Wl = (const float*)d_in[10];
    const float* c3bl = (const float*)d_in[11];
    const float* c3Wr = (const float*)d_in[12];
    const float* l1W  = (const float*)d_in[13]; const float* l1b = (const float*)d_in[14];
    const float* bn1g = (const float*)d_in[15]; const float* bn1b = (const float*)d_in[16];
    const float* l2W  = (const float*)d_in[17]; const float* l2b = (const float*)d_in[18];
    const float* bn2g = (const float*)d_in[19]; const float* bn2b = (const float*)d_in[20];
    const float* l3W  = (const float*)d_in[21]; const float* l3b = (const float*)d_in[22];
    const float* bn3g = (const float*)d_in[23]; const float* bn3b = (const float*)d_in[24];
    const float* l4W  = (const float*)d_in[25]; const float* l4b = (const float*)d_in[26];
    float* out = (float*)d_out;

    char* wsb = (char*)d_ws;
    short* Hl     = (short*)wsb; wsb += (size_t)NN * 64 * 2;
    short* Hr     = (short*)wsb; wsb += (size_t)NN * 64 * 2;
    short* e      = (short*)wsb; wsb += (size_t)NN * 64 * 2;
    float* invdeg = (float*)wsb; wsb += (size_t)NN * 4;
    float* c      = (float*)wsb; wsb += (size_t)NB * HIDN * 4;
    float* bv     = (float*)wsb; wsb += (size_t)NB * HIDN * 4;
    float* sa     = (float*)wsb; wsb += HIDN * 4;
    float* sb     = (float*)wsb; wsb += HIDN * 4;
    short* Wb1    = (short*)wsb; wsb += 128 * 512 * 2;
    short* Wb2    = (short*)wsb; wsb += 128 * 64 * 2;
    short* Wb3    = (short*)wsb; wsb += 128 * 64 * 2;
    int* row_ptr  = (int*)wsb;   wsb += (size_t)(NN + 1) * 4;
    int* csr_src  = (int*)wsb;   wsb += (size_t)NE * 4;
    int* buk_base = (int*)wsb;   wsb += (NBUK + 1) * 4;
    int* gstart   = (int*)wsb;   wsb += (NB + 1) * 4;
    // scratch aliased into buffers dead during CSR build:
    int* bpack      = (int*)Hl;  // NE ints = 12.8 MB == sizeof(Hl)
    int* block_hist = (int*)e;   // 200 KB

    // ---- CSR build: bucketed counting sort ----
    bukhist_kernel<<<NBLK_E, 256, 0, stream>>>(dst, block_hist);
    bukoff_kernel<<<1, NBUK, 0, stream>>>(block_hist, buk_base);
    bukscat_kernel<<<NBLK_E, 256, 0, stream>>>(src, dst, block_hist, bpack);
    bukfin_kernel<<<NBUK, 256, 0, stream>>>(buk_base, bpack, row_ptr, invdeg, csr_src);

    // ---- graph segment table ----
    gseg_kernel<<<(NN + 255) / 256, 256, 0, stream>>>(batch, gstart);

    // ---- weight prep ----
    wprep_kernel<<<(128 * 512 + 255) / 256, 256, 0, stream>>>(c1Wl, c1Wr, Wb1, DIN, 512);
    wprep_kernel<<<(128 * 64 + 255) / 256, 256, 0, stream>>>(c2Wl, c2Wr, Wb2, DH, 64);
    wprep_kernel<<<(128 * 64 + 255) / 256, 256, 0, stream>>>(c3Wl, c3Wr, Wb3, DH, 64);

    const int GB = (NN + 63) / 64;
    const int GGB = (NN + 3) / 4;

    // conv1
    gemm_mfma_pipe<512, DIN, true><<<GB, 256, 0, stream>>>(x, Wb1, Hl, Hr);
    gather_kernel<<<GGB, 256, 0, stream>>>(row_ptr, csr_src, Hl, Hr, invdeg, c1bl, e);
    // conv2
    gemm64_mfma<<<GB, 256, 0, stream>>>(e, Wb2, Hl, Hr);
    gather_kernel<<<GGB, 256, 0, stream>>>(row_ptr, csr_src, Hl, Hr, invdeg, c2bl, e);
    // conv3
    gemm64_mfma<<<GB, 256, 0, stream>>>(e, Wb3, Hl, Hr);
    gather_kernel<<<GGB, 256, 0, stream>>>(row_ptr, csr_src, Hl, Hr, invdeg, c3bl, e);

    // pool -> bv holds c0 [512,64] fp32
    pool_seg<<<NB, 256, 0, stream>>>(e, gstart, bv);

    // head
    lin_kernel<<<(NB * 200 + 255) / 256, 256, 0, stream>>>(bv, l1W, l1b, c, 64, 200);
    bnstats_kernel<<<200, 256, 0, stream>>>(c, bn1g, bn1b, sa, sb, 200);
    bnapply_kernel<<<(NB * 200 + 255) / 256, 256, 0, stream>>>(c, sa, sb, bv, 200);

    lin_kernel<<<(NB * 100 + 255) / 256, 256, 0, stream>>>(bv, l2W, l2b, c, 200, 100);
    bnstats_kernel<<<100, 256, 0, stream>>>(c, bn2g, bn2b, sa, sb, 100);
    bnapply_kernel<<<(NB * 100 + 255) / 256, 256, 0, stream>>>(c, sa, sb, bv, 100);

    lin_kernel<<<(NB * 100 + 255) / 256, 256, 0, stream>>>(bv, l3W, l3b, c, 100, 100);
    bnstats_kernel<<<100, 256, 0, stream>>>(c, bn3g, bn3b, sa, sb, 100);
    bnapply_kernel<<<(NB * 100 + 255) / 256, 256, 0, stream>>>(c, sa, sb, bv, 100);

    lin_kernel<<<(NB * 80 + 255) / 256, 256, 0, stream>>>(bv, l4W, l4b, out, 100, 80);
}